// Round 9
// baseline (290.026 us; speedup 1.0000x reference)
//
#include <hip/hip_runtime.h>
#include <hip/hip_bf16.h>
#include <hip/hip_fp16.h>
#include <math.h>

// AGDN: 2-layer graph attention. N=100000, E=1600000, IN=128, HID=16, HEADS=4, OUT=64.
// CSR via fixed-capacity bucket sort (binA: direct global scatter); layer-1 GEMM on
// MFMA with att-vectors folded into B, K-SPLIT B staging (20.7KB LDS -> 7 blocks/CU),
// LDS-staged vector epilogue; layer-2 GEMM commuted past aggregation;
// aggs: 8 dst/wave, batch-8 f16 gathers, agg1 src-broadcast via shfl (16.6KB LDS).
#define NN 100000
#define EE 1600000
#define IN_DIM 128
#define HID 16
#define HEADS 4
#define D1 64
#define OUT_DIM 64
#define SLOPE 0.2f

#define NB 391                 // ceil(N/256) buckets of 256 nodes
#define BCAP 5120              // bucket capacity (mean 4092, +16 sigma)
#define BINA_CHUNK 4096
#define BINA_BLOCKS ((EE + BINA_CHUNK - 1) / BINA_CHUNK)   // 391
#define NODE_BLOCKS ((NN + 63) / 64)                        // 1563
#define AGG_BLOCKS (NN / 32)                                // 3125 (exact)

#define W1COLS 144             // 64 xlin | 64 residual | 4 al | 4 ar | 8 pad
#define LDBH 144               // node1 half-K row stride: 64 k * 2B = 128B + 16B pad
#define LDB2 144               // node3: 64 bf16 = 128B + 16B pad
#define SEPI 72                // node1 epilogue stage stride (f16): 144B rows

typedef __attribute__((ext_vector_type(8))) short bf16x8;
typedef __attribute__((ext_vector_type(4))) float f32x4;

__device__ __forceinline__ float leaky(float v) { return v > 0.f ? v : SLOPE * v; }
__device__ __forceinline__ unsigned short f2bf(float f) {
    __hip_bfloat16 h = __float2bfloat16(f);
    return *(unsigned short*)&h;
}
__device__ __forceinline__ __half2 u2h2(unsigned u) {
    union { unsigned u; __half2 h; } c; c.u = u; return c.h;
}
__device__ __forceinline__ bf16x8 pack8(float4 a, float4 b) {
    bf16x8 r;
    r[0] = (short)f2bf(a.x); r[1] = (short)f2bf(a.y);
    r[2] = (short)f2bf(a.z); r[3] = (short)f2bf(a.w);
    r[4] = (short)f2bf(b.x); r[5] = (short)f2bf(b.y);
    r[6] = (short)f2bf(b.z); r[7] = (short)f2bf(b.w);
    return r;
}

// ====== Prep: bucket cursors (b0) + W1/resW/att-fold bf16 (b1) + W2 (b2) ====
__global__ void prep_kernel(int* __restrict__ bucket_cursor,
                            const float* __restrict__ W1,
                            const float* __restrict__ resW,
                            const float* __restrict__ W2,
                            const float* __restrict__ attl1,
                            const float* __restrict__ attr1,
                            const float* __restrict__ attl2,
                            const float* __restrict__ attr2,
                            unsigned short* __restrict__ Wtb,
                            unsigned short* __restrict__ W2tb,
                            float* __restrict__ vl, float* __restrict__ vr) {
    int t = threadIdx.x;
    if (blockIdx.x == 0) {
        if (t < NB) bucket_cursor[t] = t * BCAP;
    } else if (blockIdx.x == 1) {
        for (int idx = t; idx < W1COLS * 128; idx += 512) {
            int col = idx >> 7, k = idx & 127;
            float w = 0.f;
            if (col < 64) {
                w = W1[k * 64 + col];
            } else if (col < 128) {
                w = resW[k * 64 + (col - 64)];
            } else if (col < 132) {
                int hh = col - 128;
                for (int c = 0; c < HID; c++)
                    w += W1[k * 64 + hh * HID + c] * attl1[hh * HID + c];
            } else if (col < 136) {
                int hh = col - 132;
                for (int c = 0; c < HID; c++)
                    w += W1[k * 64 + hh * HID + c] * attr1[hh * HID + c];
            }
            Wtb[idx] = f2bf(w);
        }
    } else {
        for (int idx = t; idx < 64 * 64; idx += 512) {
            int col = idx >> 6, k = idx & 63;
            W2tb[idx] = f2bf(W2[k * 64 + col]);
        }
        if (t < D1) {
            float a = 0.f, b = 0.f;
            for (int o = 0; o < OUT_DIM; o++) {
                float w = W2[t * OUT_DIM + o];
                a += w * attl2[o];
                b += w * attr2[o];
            }
            vl[t] = a; vr[t] = b;
        }
    }
}

// ============ fusedA: grid union of binA (multisplit) and node1 (MFMA) ============
__device__ __forceinline__ void binA_body(char* smem, int bid,
        const int* __restrict__ src, const int* __restrict__ dst,
        int* __restrict__ bucket_cursor, unsigned* __restrict__ binned) {
    int* lhist = (int*)smem;          // 512 ints
    int* lcur  = lhist + 512;         // 512 ints
    int* gbase = lcur + 512;          // 512 ints (6KB total)
    int t = threadIdx.x;
    lhist[t] = 0; lhist[t + 256] = 0;
    lcur[t] = 0;  lcur[t + 256] = 0;
    __syncthreads();
    int e0 = bid * BINA_CHUNK;
    unsigned pk[16];
    unsigned short bk[16];
#pragma unroll
    for (int i = 0; i < 16; i++) {
        int e = e0 + t + i * 256;
        if (e < EE) {
            int d = dst[e], s = src[e];
            int b = d >> 8;
            pk[i] = ((unsigned)(d & 255) << 24) | (unsigned)s;
            bk[i] = (unsigned short)b;
            atomicAdd(&lhist[b], 1);
        } else bk[i] = 0xFFFFu;
    }
    __syncthreads();
    int c1 = lhist[t], c2 = lhist[t + 256];
    if (c1) gbase[t] = atomicAdd(&bucket_cursor[t], c1);
    if (c2) gbase[t + 256] = atomicAdd(&bucket_cursor[t + 256], c2);
    __syncthreads();
#pragma unroll
    for (int i = 0; i < 16; i++) {
        if (bk[i] != 0xFFFFu) {
            int b = bk[i];
            int pos = atomicAdd(&lcur[b], 1);
            int idx = gbase[b] + pos;
            if (idx < (b + 1) * BCAP) binned[idx] = pk[i];  // overflow guard (~never)
        }
    }
}

__device__ __forceinline__ void node1_body(char* smemB, int bid,
        const float* __restrict__ x, const unsigned short* __restrict__ Wtb,
        const float* __restrict__ b1, __half* __restrict__ xlin1h,
        __half* __restrict__ acc1h, float* __restrict__ al1,
        float* __restrict__ ar1) {
    int t = threadIdx.x;
    int base = bid * 64;
    int wave = t >> 6, lane = t & 63;
    int quad = lane >> 4, li = lane & 15;
    int node = base + wave * 16 + li;

    // ---- issue all 8 x loads first (HBM latency; B is L2-hot) ----
    float4 xreg[8];
#pragma unroll
    for (int i = 0; i < 8; i++) xreg[i] = make_float4(0.f, 0.f, 0.f, 0.f);
    if (node < NN) {
        const float* xp = x + (size_t)node * IN_DIM + quad * 8;
#pragma unroll
        for (int kc = 0; kc < 4; kc++) {
            xreg[kc * 2]     = *(const float4*)(xp + kc * 32);
            xreg[kc * 2 + 1] = *(const float4*)(xp + kc * 32 + 4);
        }
    }

    f32x4 accs[9];
#pragma unroll
    for (int nt = 0; nt < 9; nt++) accs[nt] = (f32x4){0.f, 0.f, 0.f, 0.f};

    // ---- K-split B staging: half h holds k in [h*64,(h+1)*64), 144 rows x 144B ----
#pragma unroll
    for (int half = 0; half < 2; half++) {
        for (int i = t; i < W1COLS * 8; i += 256) {       // 1152 segs of 16B
            int row = i >> 3, seg = i & 7;
            *(uint4*)(smemB + row * LDBH + seg * 16) =
                *(const uint4*)(Wtb + row * 128 + half * 64 + seg * 8);
        }
        __syncthreads();
#pragma unroll
        for (int kcl = 0; kcl < 2; kcl++) {
            int kc = half * 2 + kcl;
            bf16x8 afrag = pack8(xreg[kc * 2], xreg[kc * 2 + 1]);
            const char* brow = smemB + kcl * 64 + quad * 16;
#pragma unroll
            for (int nt = 0; nt < 9; nt++) {
                bf16x8 bfrag = *(const bf16x8*)(brow + (nt * 16 + li) * LDBH);
                accs[nt] = __builtin_amdgcn_mfma_f32_16x16x32_bf16(afrag, bfrag, accs[nt], 0, 0, 0);
            }
        }
        __syncthreads();   // reads complete before restage/epilogue overwrite
    }

    // ---- epilogue: stage f16 in smemB at stride 72 (144B rows, no conflicts) ----
    __half* sx = (__half*)smemB;          // [64][72] f16 xlin  (9216B)
    __half* sa = sx + 64 * SEPI;          // [64][72] f16 acc   (9216B)
#pragma unroll
    for (int nt = 0; nt < 4; nt++) {
#pragma unroll
        for (int j = 0; j < 4; j++) {
            int rl = wave * 16 + quad * 4 + j;
            sx[rl * SEPI + nt * 16 + li] = __float2half(accs[nt][j]);
        }
    }
#pragma unroll
    for (int nt = 4; nt < 8; nt++) {
        int col = (nt - 4) * 16 + li;
        float bv = b1[col];
#pragma unroll
        for (int j = 0; j < 4; j++) {
            int rl = wave * 16 + quad * 4 + j;
            sa[rl * SEPI + col] = __float2half(accs[nt][j] + bv);
        }
    }
    __syncthreads();
    for (int i = t; i < 512; i += 256) {
        int row = i >> 3, seg = i & 7;
        int nd = base + row;
        if (nd < NN) {
            *(uint4*)(xlin1h + (size_t)nd * D1 + seg * 8) =
                *(const uint4*)(sx + row * SEPI + seg * 8);
            *(uint4*)(acc1h + (size_t)nd * D1 + seg * 8) =
                *(const uint4*)(sa + row * SEPI + seg * 8);
        }
    }
    int m0 = base + wave * 16;
#pragma unroll
    for (int j = 0; j < 4; j++) {
        int nd = m0 + quad * 4 + j;
        if (nd < NN) {
            if (li < 4) al1[nd * HEADS + li] = accs[8][j];
            else if (li < 8) ar1[nd * HEADS + (li - 4)] = accs[8][j];
        }
    }
}

__global__ __launch_bounds__(256, 7) void fusedA_kernel(
        const int* __restrict__ src, const int* __restrict__ dst,
        int* __restrict__ bucket_cursor, unsigned* __restrict__ binned,
        const float* __restrict__ x, const unsigned short* __restrict__ Wtb,
        const float* __restrict__ b1, __half* __restrict__ xlin1h,
        __half* __restrict__ acc1h, float* __restrict__ al1,
        float* __restrict__ ar1) {
    __shared__ __align__(16) char smem[W1COLS * LDBH];   // 20736 B -> 7 blocks/CU
    if (blockIdx.x < BINA_BLOCKS)
        binA_body(smem, blockIdx.x, src, dst, bucket_cursor, binned);
    else
        node1_body(smem, blockIdx.x - BINA_BLOCKS, x, Wtb, b1, xlin1h, acc1h, al1, ar1);
}

// ================= binB: per-bucket counting sort (shfl scan) =================
__global__ __launch_bounds__(256) void binB_kernel(const unsigned* __restrict__ binned,
                                                   const int* __restrict__ bucket_cursor,
                                                   int* __restrict__ row_ptr,
                                                   int* __restrict__ counts,
                                                   int* __restrict__ sorted_src) {
    __shared__ int lcount[256], lrow[256], lcur[256];
    __shared__ int wtot[4];
    int b = blockIdx.x, t = threadIdx.x;
    int start = b * BCAP;
    int cnt = bucket_cursor[b] - start;
    if (cnt > BCAP) cnt = BCAP;
    lcount[t] = 0;
    __syncthreads();
    for (int i = t; i < cnt; i += 256) {
        atomicAdd(&lcount[binned[start + i] >> 24], 1);
    }
    __syncthreads();
    int v = lcount[t];
    int lane = t & 63, wv = t >> 6;
    int inc = v;
#pragma unroll
    for (int off = 1; off < 64; off <<= 1) {
        int n = __shfl_up(inc, off, 64);
        if (lane >= off) inc += n;
    }
    if (lane == 63) wtot[wv] = inc;
    __syncthreads();
    int wbase = 0;
#pragma unroll
    for (int i = 0; i < 4; i++) if (i < wv) wbase += wtot[i];
    int ex = wbase + inc - v;
    lrow[t] = ex;
    lcur[t] = 0;
    int node = (b << 8) + t;
    if (node < NN) {
        row_ptr[node] = start + ex;
        counts[node] = v;
    }
    __syncthreads();
    for (int i = t; i < cnt; i += 256) {
        unsigned p = binned[start + i];
        int low = p >> 24;
        int pos = atomicAdd(&lcur[low], 1);
        sorted_src[start + lrow[low] + pos] = (int)(p & 0xFFFFFFu);
    }
}

// ====== Fused aggregation, layer 1 (H=4,C=16) + residual + ELU + L2 dots ======
// 8 dst nodes per wave: g=lane>>3 node, li=lane&7 owns channels li*8..+7 (head li>>1).
// pass-2 batch-8; src indices re-read from L1-hot sorted_src + shfl broadcast.
__global__ __launch_bounds__(256) void agg1_kernel(
        const int* __restrict__ sorted_src, const int* __restrict__ row_ptr,
        const int* __restrict__ counts,
        const float* __restrict__ al1, const float* __restrict__ ar1,
        const __half* __restrict__ xlin1h, const __half* __restrict__ acc1h,
        __half* __restrict__ hh,
        const float* __restrict__ vl, const float* __restrict__ vr,
        float* __restrict__ al2, float* __restrict__ ar2) {
    __shared__ __half s_alpha[4][8][65][4];   // 16640 B
    int w = threadIdx.x >> 6, lane = threadIdx.x & 63;
    int g = lane >> 3, li = lane & 7;
    int d = blockIdx.x * 32 + w * 8 + g;      // AGG_BLOCKS*32 == NN exactly
    int rs = row_ptr[d];
    int deg = counts[d];
    const float4 arv = *(const float4*)(ar1 + d * 4);
    int h = li >> 1;

    int maxdeg = deg;
    maxdeg = max(maxdeg, __shfl_xor(maxdeg, 8, 64));
    maxdeg = max(maxdeg, __shfl_xor(maxdeg, 16, 64));
    maxdeg = max(maxdeg, __shfl_xor(maxdeg, 32, 64));
    bool big = maxdeg > 64;   // wave-uniform, ~never

    // ---- pass 1: raw exps (logits bounded) to LDS, per-group sums ----
    float s0 = 0.f, s1 = 0.f, s2 = 0.f, s3 = 0.f;
    if (!big) {
        for (int e = li; e < maxdeg; e += 8) {
            if (e < deg) {
                int s = sorted_src[rs + e];
                const float4 alv = *(const float4*)(al1 + s * 4);
                float e0 = __expf(leaky(alv.x + arv.x));
                float e1 = __expf(leaky(alv.y + arv.y));
                float e2 = __expf(leaky(alv.z + arv.z));
                float e3 = __expf(leaky(alv.w + arv.w));
                s0 += e0; s1 += e1; s2 += e2; s3 += e3;
                __half2 h01 = __floats2half2_rn(e0, e1);
                __half2 h23 = __floats2half2_rn(e2, e3);
                *(uint2*)&s_alpha[w][g][e][0] =
                    make_uint2(*(unsigned*)&h01, *(unsigned*)&h23);
            }
        }
    } else {
        for (int e = li; e < deg; e += 8) {
            int s = sorted_src[rs + e];
            const float4 alv = *(const float4*)(al1 + s * 4);
            s0 += __expf(leaky(alv.x + arv.x));
            s1 += __expf(leaky(alv.y + arv.y));
            s2 += __expf(leaky(alv.z + arv.z));
            s3 += __expf(leaky(alv.w + arv.w));
        }
    }
#pragma unroll
    for (int off = 1; off < 8; off <<= 1) {
        s0 += __shfl_xor(s0, off, 64);
        s1 += __shfl_xor(s1, off, 64);
        s2 += __shfl_xor(s2, off, 64);
        s3 += __shfl_xor(s3, off, 64);
    }
    float inv0 = 0.f, inv1 = 0.f, inv2 = 0.f, inv3 = 0.f;
    if (deg > 0) {
        inv0 = 1.f / (s0 + 1e-16f); inv1 = 1.f / (s1 + 1e-16f);
        inv2 = 1.f / (s2 + 1e-16f); inv3 = 1.f / (s3 + 1e-16f);
    }
    float invh = (h == 0) ? inv0 : (h == 1) ? inv1 : (h == 2) ? inv2 : inv3;
    __half2 invh2 = __floats2half2_rn(invh, invh);
    // per-wave LDS write->read, in-order within wave: no barrier needed

    // ---- pass 2: gather-accumulate (f16 packed, 16B/lane), batch-8 ----
    __half2 a01 = __floats2half2_rn(0.f, 0.f);
    __half2 a23 = a01, a45 = a01, a67 = a01;
    float fb0=0.f, fb1=0.f, fb2=0.f, fb3=0.f, fb4=0.f, fb5=0.f, fb6=0.f, fb7=0.f;
    if (!big) {
        for (int i0 = 0; i0 < maxdeg; i0 += 8) {
            int myi = i0 + li;
            int mys = (myi < deg) ? sorted_src[rs + myi] : 0;
            int ss[8]; __half ah[8]; uint4 uu[8];
#pragma unroll
            for (int j = 0; j < 8; j++) {
                ss[j] = __shfl(mys, (g << 3) + j, 64);
                int i = i0 + j;
                ah[j] = (i < deg) ? s_alpha[w][g][i][h] : __float2half(0.f);
            }
#pragma unroll
            for (int j = 0; j < 8; j++) {
                int i = i0 + j;
                uu[j] = make_uint4(0u, 0u, 0u, 0u);
                if (i < deg) uu[j] = *(const uint4*)(xlin1h + (size_t)ss[j] * D1 + li * 8);
            }
#pragma unroll
            for (int j = 0; j < 8; j++) {
                __half2 a2 = __hmul2(__half2half2(ah[j]), invh2);
                a01 = __hfma2(a2, u2h2(uu[j].x), a01);
                a23 = __hfma2(a2, u2h2(uu[j].y), a23);
                a45 = __hfma2(a2, u2h2(uu[j].z), a45);
                a67 = __hfma2(a2, u2h2(uu[j].w), a67);
            }
        }
    } else {
        float arh = (h == 0) ? arv.x : (h == 1) ? arv.y : (h == 2) ? arv.z : arv.w;
        for (int i = 0; i < deg; i++) {
            int s = sorted_src[rs + i];
            const float4 alv = *(const float4*)(al1 + s * 4);
            float lv = (h == 0) ? alv.x : (h == 1) ? alv.y : (h == 2) ? alv.z : alv.w;
            float a = __expf(leaky(lv + arh)) * invh;
            uint4 u = *(const uint4*)(xlin1h + (size_t)s * D1 + li * 8);
            float2 x01 = __half22float2(u2h2(u.x));
            float2 x23 = __half22float2(u2h2(u.y));
            float2 x45 = __half22float2(u2h2(u.z));
            float2 x67 = __half22float2(u2h2(u.w));
            fb0 += a * x01.x; fb1 += a * x01.y; fb2 += a * x23.x; fb3 += a * x23.y;
            fb4 += a * x45.x; fb5 += a * x45.y; fb6 += a * x67.x; fb7 += a * x67.y;
        }
    }
    // ---- epilogue: + residual(f16), ELU -> h (f16), layer-2 dots ----
    float c0, c1, c2, c3, c4, c5, c6, c7;
    { float2 tv;
      tv = __half22float2(a01); c0 = tv.x + fb0; c1 = tv.y + fb1;
      tv = __half22float2(a23); c2 = tv.x + fb2; c3 = tv.y + fb3;
      tv = __half22float2(a45); c4 = tv.x + fb4; c5 = tv.y + fb5;
      tv = __half22float2(a67); c6 = tv.x + fb6; c7 = tv.y + fb7; }
    uint4 rres = *(const uint4*)(acc1h + (size_t)d * D1 + li * 8);
    { float2 tv;
      tv = __half22float2(u2h2(rres.x)); c0 += tv.x; c1 += tv.y;
      tv = __half22float2(u2h2(rres.y)); c2 += tv.x; c3 += tv.y;
      tv = __half22float2(u2h2(rres.z)); c4 += tv.x; c5 += tv.y;
      tv = __half22float2(u2h2(rres.w)); c6 += tv.x; c7 += tv.y; }
    c0 = c0 > 0.f ? c0 : (__expf(c0) - 1.f);
    c1 = c1 > 0.f ? c1 : (__expf(c1) - 1.f);
    c2 = c2 > 0.f ? c2 : (__expf(c2) - 1.f);
    c3 = c3 > 0.f ? c3 : (__expf(c3) - 1.f);
    c4 = c4 > 0.f ? c4 : (__expf(c4) - 1.f);
    c5 = c5 > 0.f ? c5 : (__expf(c5) - 1.f);
    c6 = c6 > 0.f ? c6 : (__expf(c6) - 1.f);
    c7 = c7 > 0.f ? c7 : (__expf(c7) - 1.f);
    __half2 o01 = __floats2half2_rn(c0, c1);
    __half2 o23 = __floats2half2_rn(c2, c3);
    __half2 o45 = __floats2half2_rn(c4, c5);
    __half2 o67 = __floats2half2_rn(c6, c7);
    uint4 hv = make_uint4(*(unsigned*)&o01, *(unsigned*)&o23,
                          *(unsigned*)&o45, *(unsigned*)&o67);
    *(uint4*)(hh + (size_t)d * D1 + li * 8) = hv;
    const float4 vla = *(const float4*)(vl + li * 8);
    const float4 vlb = *(const float4*)(vl + li * 8 + 4);
    const float4 vra = *(const float4*)(vr + li * 8);
    const float4 vrb = *(const float4*)(vr + li * 8 + 4);
    float pl = c0 * vla.x + c1 * vla.y + c2 * vla.z + c3 * vla.w
             + c4 * vlb.x + c5 * vlb.y + c6 * vlb.z + c7 * vlb.w;
    float pr = c0 * vra.x + c1 * vra.y + c2 * vra.z + c3 * vra.w
             + c4 * vrb.x + c5 * vrb.y + c6 * vrb.z + c7 * vrb.w;
#pragma unroll
    for (int off = 1; off < 8; off <<= 1) {
        pl += __shfl_xor(pl, off, 64);
        pr += __shfl_xor(pr, off, 64);
    }
    if (li == 0) { al2[d] = pl; ar2[d] = pr; }
}

// ====== Fused aggregation, layer 2 (H=1, C=64): gathers h, writes hsum bf16 ======
__global__ __launch_bounds__(256) void agg2_kernel(
        const int* __restrict__ sorted_src, const int* __restrict__ row_ptr,
        const int* __restrict__ counts,
        const float* __restrict__ al2, const float* __restrict__ ar2,
        const __half* __restrict__ hh,
        unsigned short* __restrict__ hsum) {
    __shared__ __half s_alpha[4][8][65];   // 4160 B
    __shared__ int    s_src[4][8][65];     // 8320 B
    int w = threadIdx.x >> 6, lane = threadIdx.x & 63;
    int g = lane >> 3, li = lane & 7;
    int d = blockIdx.x * 32 + w * 8 + g;
    int rs = row_ptr[d];
    int deg = counts[d];
    float ard = ar2[d];

    int maxdeg = deg;
    maxdeg = max(maxdeg, __shfl_xor(maxdeg, 8, 64));
    maxdeg = max(maxdeg, __shfl_xor(maxdeg, 16, 64));
    maxdeg = max(maxdeg, __shfl_xor(maxdeg, 32, 64));
    bool big = maxdeg > 64;

    float ssum = 0.f;
    if (!big) {
        for (int e = li; e < maxdeg; e += 8) {
            if (e < deg) {
                int s = sorted_src[rs + e];
                float ex = __expf(leaky(al2[s] + ard));
                ssum += ex;
                s_alpha[w][g][e] = __float2half(ex);
                s_src[w][g][e] = s;
            }
        }
    } else {
        for (int e = li; e < deg; e += 8) {
            int s = sorted_src[rs + e];
            ssum += __expf(leaky(al2[s] + ard));
        }
    }
#pragma unroll
    for (int off = 1; off < 8; off <<= 1) ssum += __shfl_xor(ssum, off, 64);
    float inv = (deg > 0) ? 1.f / (ssum + 1e-16f) : 0.f;
    __half2 inv2h = __floats2half2_rn(inv, inv);

    __half2 a01 = __floats2half2_rn(0.f, 0.f);
    __half2 a23 = a01, a45 = a01, a67 = a01;
    float fb0=0.f, fb1=0.f, fb2=0.f, fb3=0.f, fb4=0.f, fb5=0.f, fb6=0.f, fb7=0.f;
    if (!big) {
        for (int i0 = 0; i0 < maxdeg; i0 += 8) {
            int ss[8]; __half ah[8]; uint4 uu[8];
#pragma unroll
            for (int j = 0; j < 8; j++) {
                int i = i0 + j;
                bool v = i < deg;
                ss[j] = v ? s_src[w][g][i] : 0;
                ah[j] = v ? s_alpha[w][g][i] : __float2half(0.f);
            }
#pragma unroll
            for (int j = 0; j < 8; j++) {
                int i = i0 + j;
                uu[j] = make_uint4(0u, 0u, 0u, 0u);
                if (i < deg) uu[j] = *(const uint4*)(hh + (size_t)ss[j] * D1 + li * 8);
            }
#pragma unroll
            for (int j = 0; j < 8; j++) {
                __half2 a2 = __hmul2(__half2half2(ah[j]), inv2h);
                a01 = __hfma2(a2, u2h2(uu[j].x), a01);
                a23 = __hfma2(a2, u2h2(uu[j].y), a23);
                a45 = __hfma2(a2, u2h2(uu[j].z), a45);
                a67 = __hfma2(a2, u2h2(uu[j].w), a67);
            }
        }
    } else {
        for (int i = 0; i < deg; i++) {
            int s = sorted_src[rs + i];
            float a = __expf(leaky(al2[s] + ard)) * inv;
            uint4 u = *(const uint4*)(hh + (size_t)s * D1 + li * 8);
            float2 x01 = __half22float2(u2h2(u.x));
            float2 x23 = __half22float2(u2h2(u.y));
            float2 x45 = __half22float2(u2h2(u.z));
            float2 x67 = __half22float2(u2h2(u.w));
            fb0 += a * x01.x; fb1 += a * x01.y; fb2 += a * x23.x; fb3 += a * x23.y;
            fb4 += a * x45.x; fb5 += a * x45.y; fb6 += a * x67.x; fb7 += a * x67.y;
        }
    }
    // ---- epilogue: + own h[d] (layer-2 residual, pre-GEMM), write bf16 ----
    float c0, c1, c2, c3, c4, c5, c6, c7;
    { float2 tv;
      tv = __half22float2(a01); c0 = tv.x + fb0; c1 = tv.y + fb1;
      tv = __half22float2(a23); c2 = tv.x + fb2; c3 = tv.y + fb3;
      tv = __half22float2(a45); c4 = tv.x + fb4; c5 = tv.y + fb5;
      tv = __half22float2(a67); c6 = tv.x + fb6; c7 = tv.y + fb7; }
    uint4 own = *(const uint4*)(hh + (size_t)d * D1 + li * 8);
    { float2 tv;
      tv = __half22float2(u2h2(own.x)); c0 += tv.x; c1 += tv.y;
      tv = __half22float2(u2h2(own.y)); c2 += tv.x; c3 += tv.y;
      tv = __half22float2(u2h2(own.z)); c4 += tv.x; c5 += tv.y;
      tv = __half22float2(u2h2(own.w)); c6 += tv.x; c7 += tv.y; }
    union { unsigned short us[8]; uint4 u4; } hw;
    hw.us[0] = f2bf(c0); hw.us[1] = f2bf(c1); hw.us[2] = f2bf(c2); hw.us[3] = f2bf(c3);
    hw.us[4] = f2bf(c4); hw.us[5] = f2bf(c5); hw.us[6] = f2bf(c6); hw.us[7] = f2bf(c7);
    *(uint4*)(hsum + (size_t)d * D1 + li * 8) = hw.u4;
}

// ================= node3: final MFMA GEMM: out = hsum @ W2 + b2 =================
__global__ __launch_bounds__(256) void node3_kernel(
        const unsigned short* __restrict__ hsum,
        const unsigned short* __restrict__ W2tb,     // [64 cols][64 k] bf16
        const float* __restrict__ b2,
        float* __restrict__ out) {
    __shared__ char smemB[64 * LDB2];   // 9216 B
    int t = threadIdx.x;
    int base = blockIdx.x * 64;
    int wave = t >> 6, lane = t & 63;
    int quad = lane >> 4, li = lane & 15;
    int node = base + wave * 16 + li;

    uint4 breg[2];
#pragma unroll
    for (int s = 0; s < 2; s++) {
        int seg = s * 256 + t;                       // 512 = 64 rows * 8 segs
        breg[s] = *(const uint4*)(W2tb + (seg >> 3) * 64 + (seg & 7) * 8);
    }
    bf16x8 afr[2];
#pragma unroll
    for (int kc = 0; kc < 2; kc++)
#pragma unroll
        for (int i = 0; i < 8; i++) afr[kc][i] = 0;
    if (node < NN) {
        afr[0] = *(const bf16x8*)(hsum + (size_t)node * D1 + quad * 8);
        afr[1] = *(const bf16x8*)(hsum + (size_t)node * D1 + 32 + quad * 8);
    }
#pragma unroll
    for (int s = 0; s < 2; s++) {
        int seg = s * 256 + t;
        *(uint4*)(smemB + (seg >> 3) * LDB2 + (seg & 7) * 16) = breg[s];
    }
    __syncthreads();

    f32x4 accs[4];
#pragma unroll
    for (int nt = 0; nt < 4; nt++) accs[nt] = (f32x4){0.f, 0.f, 0.f, 0.f};
#pragma unroll
    for (int kc = 0; kc < 2; kc++) {
        const char* brow = smemB + kc * 64 + quad * 16;
#pragma unroll
        for (int nt = 0; nt < 4; nt++) {
            bf16x8 bfrag = *(const bf16x8*)(brow + (nt * 16 + li) * LDB2);
            accs[nt] = __builtin_amdgcn_mfma_f32_16x16x32_bf16(afr[kc], bfrag, accs[nt], 0, 0, 0);
        }
    }

    int m0 = base + wave * 16;
#pragma unroll
    for (int nt = 0; nt < 4; nt++) {
        int col = nt * 16 + li;
        float bv = b2[col];
#pragma unroll
        for (int j = 0; j < 4; j++) {
            int nd = m0 + quad * 4 + j;
            if (nd < NN) out[(size_t)nd * OUT_DIM + col] = accs[nt][j] + bv;
        }
    }
}

extern "C" void kernel_launch(void* const* d_in, const int* in_sizes, int n_in,
                              void* d_out, int out_size, void* d_ws, size_t ws_size,
                              hipStream_t stream) {
    const float* x     = (const float*)d_in[0];
    const int*   eidx  = (const int*)d_in[1];
    const float* W1    = (const float*)d_in[2];
    const float* attl1 = (const float*)d_in[3];
    const float* attr1 = (const float*)d_in[4];
    const float* resW1 = (const float*)d_in[5];
    const float* b1    = (const float*)d_in[6];
    const float* W2    = (const float*)d_in[7];
    const float* attl2 = (const float*)d_in[8];
    const float* attr2 = (const float*)d_in[9];
    const float* b2    = (const float*)d_in[10];

    const int* src = eidx;
    const int* dst = eidx + EE;

    // workspace layout
    __half* xlin1h = (__half*)d_ws;                            // N*64 f16
    __half* acc1h  = xlin1h + (size_t)NN * D1;                 // N*64 f16 residual
    __half* hh     = acc1h + (size_t)NN * D1;                  // N*64 f16 h
    unsigned short* hsum = (unsigned short*)(hh + (size_t)NN * D1);  // N*64 bf16
    float* al1   = (float*)(hsum + (size_t)NN * D1);           // N*4
    float* ar1   = al1 + (size_t)NN * HEADS;                   // N*4
    float* al2   = ar1 + (size_t)NN * HEADS;                   // N
    float* ar2   = al2 + NN;                                   // N
    float* vl    = ar2 + NN;                                   // 64
    float* vr    = vl + D1;                                    // 64
    unsigned short* Wtb  = (unsigned short*)(vr + D1);         // 144*128 bf16
    unsigned short* W2tb = Wtb + W1COLS * 128;                 // 64*64 bf16
    int* counts        = (int*)(W2tb + 64 * 64);               // N
    int* row_ptr       = counts + NN;                          // N
    int* bucket_cursor = row_ptr + NN;                         // 512
    int* sorted_src    = bucket_cursor + 512;                  // NB*BCAP = 2001920
    unsigned* binned = (unsigned*)d_out;    // NB*BCAP u32 = 8 MB; dead after binB

    float* out = (float*)d_out;

    // ---- prep + CSR build (binA fused with node1) ----
    prep_kernel<<<3, 512, 0, stream>>>(bucket_cursor, W1, resW1, W2,
                                       attl1, attr1, attl2, attr2,
                                       Wtb, W2tb, vl, vr);
    fusedA_kernel<<<BINA_BLOCKS + NODE_BLOCKS, 256, 0, stream>>>(
        src, dst, bucket_cursor, binned,
        x, Wtb, b1, xlin1h, acc1h, al1, ar1);
    binB_kernel<<<NB, 256, 0, stream>>>(binned, bucket_cursor,
                                        row_ptr, counts, sorted_src);

    // ---- layer 1 aggregation (+ residual + ELU + layer-2 dots) ----
    agg1_kernel<<<AGG_BLOCKS, 256, 0, stream>>>(sorted_src, row_ptr, counts,
                                                al1, ar1, xlin1h, acc1h, hh,
                                                vl, vr, al2, ar2);

    // ---- layer 2: aggregate h, then single GEMM ----
    agg2_kernel<<<AGG_BLOCKS, 256, 0, stream>>>(sorted_src, row_ptr, counts,
                                                al2, ar2, hh, hsum);
    node3_kernel<<<NODE_BLOCKS, 256, 0, stream>>>(hsum, W2tb, b2, out);
}

// Round 11
// 246.975 us; speedup vs baseline: 1.1743x; 1.1743x over previous
//
#include <hip/hip_runtime.h>
#include <hip/hip_bf16.h>
#include <hip/hip_fp16.h>
#include <math.h>

// AGDN: 2-layer graph attention. N=100000, E=1600000, IN=128, HID=16, HEADS=4, OUT=64.
// CSR via fixed-capacity bucket sort (binA: direct global scatter); layer-1 GEMM on
// MFMA with att-vectors folded into B, K-SPLIT B staging (20.7KB LDS -> 7 blocks/CU),
// LDS-staged vector epilogue; layer-2 GEMM commuted past aggregation;
// aggs: 8 dst/wave, batch-8 f16 gathers, agg1 src-broadcast via shfl (16.6KB LDS).
// NOTE: __launch_bounds__ 2nd arg is min waves/EU (SIMD), NOT blocks/CU — (256,7)
// capped VGPR at 64 and spilled (R9 regression). Keep (256,4).
#define NN 100000
#define EE 1600000
#define IN_DIM 128
#define HID 16
#define HEADS 4
#define D1 64
#define OUT_DIM 64
#define SLOPE 0.2f

#define NB 391                 // ceil(N/256) buckets of 256 nodes
#define BCAP 5120              // bucket capacity (mean 4092, +16 sigma)
#define BINA_CHUNK 4096
#define BINA_BLOCKS ((EE + BINA_CHUNK - 1) / BINA_CHUNK)   // 391
#define NODE_BLOCKS ((NN + 63) / 64)                        // 1563
#define AGG_BLOCKS (NN / 32)                                // 3125 (exact)

#define W1COLS 144             // 64 xlin | 64 residual | 4 al | 4 ar | 8 pad
#define LDBH 144               // node1 half-K row stride: 64 k * 2B = 128B + 16B pad
#define LDB2 144               // node3: 64 bf16 = 128B + 16B pad
#define SEPI 72                // node1 epilogue stage stride (f16): 144B rows

typedef __attribute__((ext_vector_type(8))) short bf16x8;
typedef __attribute__((ext_vector_type(4))) float f32x4;

__device__ __forceinline__ float leaky(float v) { return v > 0.f ? v : SLOPE * v; }
__device__ __forceinline__ unsigned short f2bf(float f) {
    __hip_bfloat16 h = __float2bfloat16(f);
    return *(unsigned short*)&h;
}
__device__ __forceinline__ __half2 u2h2(unsigned u) {
    union { unsigned u; __half2 h; } c; c.u = u; return c.h;
}
__device__ __forceinline__ bf16x8 pack8(float4 a, float4 b) {
    bf16x8 r;
    r[0] = (short)f2bf(a.x); r[1] = (short)f2bf(a.y);
    r[2] = (short)f2bf(a.z); r[3] = (short)f2bf(a.w);
    r[4] = (short)f2bf(b.x); r[5] = (short)f2bf(b.y);
    r[6] = (short)f2bf(b.z); r[7] = (short)f2bf(b.w);
    return r;
}

// ====== Prep: bucket cursors (b0) + W1/resW/att-fold bf16 (b1) + W2 (b2) ====
__global__ void prep_kernel(int* __restrict__ bucket_cursor,
                            const float* __restrict__ W1,
                            const float* __restrict__ resW,
                            const float* __restrict__ W2,
                            const float* __restrict__ attl1,
                            const float* __restrict__ attr1,
                            const float* __restrict__ attl2,
                            const float* __restrict__ attr2,
                            unsigned short* __restrict__ Wtb,
                            unsigned short* __restrict__ W2tb,
                            float* __restrict__ vl, float* __restrict__ vr) {
    int t = threadIdx.x;
    if (blockIdx.x == 0) {
        if (t < NB) bucket_cursor[t] = t * BCAP;
    } else if (blockIdx.x == 1) {
        for (int idx = t; idx < W1COLS * 128; idx += 512) {
            int col = idx >> 7, k = idx & 127;
            float w = 0.f;
            if (col < 64) {
                w = W1[k * 64 + col];
            } else if (col < 128) {
                w = resW[k * 64 + (col - 64)];
            } else if (col < 132) {
                int hh = col - 128;
                for (int c = 0; c < HID; c++)
                    w += W1[k * 64 + hh * HID + c] * attl1[hh * HID + c];
            } else if (col < 136) {
                int hh = col - 132;
                for (int c = 0; c < HID; c++)
                    w += W1[k * 64 + hh * HID + c] * attr1[hh * HID + c];
            }
            Wtb[idx] = f2bf(w);
        }
    } else {
        for (int idx = t; idx < 64 * 64; idx += 512) {
            int col = idx >> 6, k = idx & 63;
            W2tb[idx] = f2bf(W2[k * 64 + col]);
        }
        if (t < D1) {
            float a = 0.f, b = 0.f;
            for (int o = 0; o < OUT_DIM; o++) {
                float w = W2[t * OUT_DIM + o];
                a += w * attl2[o];
                b += w * attr2[o];
            }
            vl[t] = a; vr[t] = b;
        }
    }
}

// ============ fusedA: grid union of binA (multisplit) and node1 (MFMA) ============
__device__ __forceinline__ void binA_body(char* smem, int bid,
        const int* __restrict__ src, const int* __restrict__ dst,
        int* __restrict__ bucket_cursor, unsigned* __restrict__ binned) {
    int* lhist = (int*)smem;          // 512 ints
    int* lcur  = lhist + 512;         // 512 ints
    int* gbase = lcur + 512;          // 512 ints (6KB total)
    int t = threadIdx.x;
    lhist[t] = 0; lhist[t + 256] = 0;
    lcur[t] = 0;  lcur[t + 256] = 0;
    __syncthreads();
    int e0 = bid * BINA_CHUNK;
    unsigned pk[16];
    unsigned short bk[16];
#pragma unroll
    for (int i = 0; i < 16; i++) {
        int e = e0 + t + i * 256;
        if (e < EE) {
            int d = dst[e], s = src[e];
            int b = d >> 8;
            pk[i] = ((unsigned)(d & 255) << 24) | (unsigned)s;
            bk[i] = (unsigned short)b;
            atomicAdd(&lhist[b], 1);
        } else bk[i] = 0xFFFFu;
    }
    __syncthreads();
    int c1 = lhist[t], c2 = lhist[t + 256];
    if (c1) gbase[t] = atomicAdd(&bucket_cursor[t], c1);
    if (c2) gbase[t + 256] = atomicAdd(&bucket_cursor[t + 256], c2);
    __syncthreads();
#pragma unroll
    for (int i = 0; i < 16; i++) {
        if (bk[i] != 0xFFFFu) {
            int b = bk[i];
            int pos = atomicAdd(&lcur[b], 1);
            int idx = gbase[b] + pos;
            if (idx < (b + 1) * BCAP) binned[idx] = pk[i];  // overflow guard (~never)
        }
    }
}

__device__ __forceinline__ void node1_body(char* smemB, int bid,
        const float* __restrict__ x, const unsigned short* __restrict__ Wtb,
        const float* __restrict__ b1, __half* __restrict__ xlin1h,
        __half* __restrict__ acc1h, float* __restrict__ al1,
        float* __restrict__ ar1) {
    int t = threadIdx.x;
    int base = bid * 64;
    int wave = t >> 6, lane = t & 63;
    int quad = lane >> 4, li = lane & 15;
    int node = base + wave * 16 + li;

    // ---- issue all 8 x loads first (HBM latency; B is L2-hot) ----
    float4 xreg[8];
#pragma unroll
    for (int i = 0; i < 8; i++) xreg[i] = make_float4(0.f, 0.f, 0.f, 0.f);
    if (node < NN) {
        const float* xp = x + (size_t)node * IN_DIM + quad * 8;
#pragma unroll
        for (int kc = 0; kc < 4; kc++) {
            xreg[kc * 2]     = *(const float4*)(xp + kc * 32);
            xreg[kc * 2 + 1] = *(const float4*)(xp + kc * 32 + 4);
        }
    }

    f32x4 accs[9];
#pragma unroll
    for (int nt = 0; nt < 9; nt++) accs[nt] = (f32x4){0.f, 0.f, 0.f, 0.f};

    // ---- K-split B staging: half h holds k in [h*64,(h+1)*64), 144 rows x 144B ----
#pragma unroll
    for (int half = 0; half < 2; half++) {
        for (int i = t; i < W1COLS * 8; i += 256) {       // 1152 segs of 16B
            int row = i >> 3, seg = i & 7;
            *(uint4*)(smemB + row * LDBH + seg * 16) =
                *(const uint4*)(Wtb + row * 128 + half * 64 + seg * 8);
        }
        __syncthreads();
#pragma unroll
        for (int kcl = 0; kcl < 2; kcl++) {
            int kc = half * 2 + kcl;
            bf16x8 afrag = pack8(xreg[kc * 2], xreg[kc * 2 + 1]);
            const char* brow = smemB + kcl * 64 + quad * 16;
#pragma unroll
            for (int nt = 0; nt < 9; nt++) {
                bf16x8 bfrag = *(const bf16x8*)(brow + (nt * 16 + li) * LDBH);
                accs[nt] = __builtin_amdgcn_mfma_f32_16x16x32_bf16(afrag, bfrag, accs[nt], 0, 0, 0);
            }
        }
        __syncthreads();   // reads complete before restage/epilogue overwrite
    }

    // ---- epilogue: stage f16 in smemB at stride 72 (144B rows, no conflicts) ----
    __half* sx = (__half*)smemB;          // [64][72] f16 xlin  (9216B)
    __half* sa = sx + 64 * SEPI;          // [64][72] f16 acc   (9216B)
#pragma unroll
    for (int nt = 0; nt < 4; nt++) {
#pragma unroll
        for (int j = 0; j < 4; j++) {
            int rl = wave * 16 + quad * 4 + j;
            sx[rl * SEPI + nt * 16 + li] = __float2half(accs[nt][j]);
        }
    }
#pragma unroll
    for (int nt = 4; nt < 8; nt++) {
        int col = (nt - 4) * 16 + li;
        float bv = b1[col];
#pragma unroll
        for (int j = 0; j < 4; j++) {
            int rl = wave * 16 + quad * 4 + j;
            sa[rl * SEPI + col] = __float2half(accs[nt][j] + bv);
        }
    }
    __syncthreads();
    for (int i = t; i < 512; i += 256) {
        int row = i >> 3, seg = i & 7;
        int nd = base + row;
        if (nd < NN) {
            *(uint4*)(xlin1h + (size_t)nd * D1 + seg * 8) =
                *(const uint4*)(sx + row * SEPI + seg * 8);
            *(uint4*)(acc1h + (size_t)nd * D1 + seg * 8) =
                *(const uint4*)(sa + row * SEPI + seg * 8);
        }
    }
    int m0 = base + wave * 16;
#pragma unroll
    for (int j = 0; j < 4; j++) {
        int nd = m0 + quad * 4 + j;
        if (nd < NN) {
            if (li < 4) al1[nd * HEADS + li] = accs[8][j];
            else if (li < 8) ar1[nd * HEADS + (li - 4)] = accs[8][j];
        }
    }
}

__global__ __launch_bounds__(256, 4) void fusedA_kernel(
        const int* __restrict__ src, const int* __restrict__ dst,
        int* __restrict__ bucket_cursor, unsigned* __restrict__ binned,
        const float* __restrict__ x, const unsigned short* __restrict__ Wtb,
        const float* __restrict__ b1, __half* __restrict__ xlin1h,
        __half* __restrict__ acc1h, float* __restrict__ al1,
        float* __restrict__ ar1) {
    __shared__ __align__(16) char smem[W1COLS * LDBH];   // 20736 B (LDS: 7 blocks/CU)
    if (blockIdx.x < BINA_BLOCKS)
        binA_body(smem, blockIdx.x, src, dst, bucket_cursor, binned);
    else
        node1_body(smem, blockIdx.x - BINA_BLOCKS, x, Wtb, b1, xlin1h, acc1h, al1, ar1);
}

// ================= binB: per-bucket counting sort (shfl scan) =================
__global__ __launch_bounds__(256) void binB_kernel(const unsigned* __restrict__ binned,
                                                   const int* __restrict__ bucket_cursor,
                                                   int* __restrict__ row_ptr,
                                                   int* __restrict__ counts,
                                                   int* __restrict__ sorted_src) {
    __shared__ int lcount[256], lrow[256], lcur[256];
    __shared__ int wtot[4];
    int b = blockIdx.x, t = threadIdx.x;
    int start = b * BCAP;
    int cnt = bucket_cursor[b] - start;
    if (cnt > BCAP) cnt = BCAP;
    lcount[t] = 0;
    __syncthreads();
    for (int i = t; i < cnt; i += 256) {
        atomicAdd(&lcount[binned[start + i] >> 24], 1);
    }
    __syncthreads();
    int v = lcount[t];
    int lane = t & 63, wv = t >> 6;
    int inc = v;
#pragma unroll
    for (int off = 1; off < 64; off <<= 1) {
        int n = __shfl_up(inc, off, 64);
        if (lane >= off) inc += n;
    }
    if (lane == 63) wtot[wv] = inc;
    __syncthreads();
    int wbase = 0;
#pragma unroll
    for (int i = 0; i < 4; i++) if (i < wv) wbase += wtot[i];
    int ex = wbase + inc - v;
    lrow[t] = ex;
    lcur[t] = 0;
    int node = (b << 8) + t;
    if (node < NN) {
        row_ptr[node] = start + ex;
        counts[node] = v;
    }
    __syncthreads();
    for (int i = t; i < cnt; i += 256) {
        unsigned p = binned[start + i];
        int low = p >> 24;
        int pos = atomicAdd(&lcur[low], 1);
        sorted_src[start + lrow[low] + pos] = (int)(p & 0xFFFFFFu);
    }
}

// ====== Fused aggregation, layer 1 (H=4,C=16) + residual + ELU + L2 dots ======
// 8 dst nodes per wave: g=lane>>3 node, li=lane&7 owns channels li*8..+7 (head li>>1).
// pass-2 batch-8; src indices re-read from L1-hot sorted_src + shfl broadcast.
__global__ __launch_bounds__(256) void agg1_kernel(
        const int* __restrict__ sorted_src, const int* __restrict__ row_ptr,
        const int* __restrict__ counts,
        const float* __restrict__ al1, const float* __restrict__ ar1,
        const __half* __restrict__ xlin1h, const __half* __restrict__ acc1h,
        __half* __restrict__ hh,
        const float* __restrict__ vl, const float* __restrict__ vr,
        float* __restrict__ al2, float* __restrict__ ar2) {
    __shared__ __half s_alpha[4][8][65][4];   // 16640 B
    int w = threadIdx.x >> 6, lane = threadIdx.x & 63;
    int g = lane >> 3, li = lane & 7;
    int d = blockIdx.x * 32 + w * 8 + g;      // AGG_BLOCKS*32 == NN exactly
    int rs = row_ptr[d];
    int deg = counts[d];
    const float4 arv = *(const float4*)(ar1 + d * 4);
    int h = li >> 1;

    int maxdeg = deg;
    maxdeg = max(maxdeg, __shfl_xor(maxdeg, 8, 64));
    maxdeg = max(maxdeg, __shfl_xor(maxdeg, 16, 64));
    maxdeg = max(maxdeg, __shfl_xor(maxdeg, 32, 64));
    bool big = maxdeg > 64;   // wave-uniform, ~never

    // ---- pass 1: raw exps (logits bounded) to LDS, per-group sums ----
    float s0 = 0.f, s1 = 0.f, s2 = 0.f, s3 = 0.f;
    if (!big) {
        for (int e = li; e < maxdeg; e += 8) {
            if (e < deg) {
                int s = sorted_src[rs + e];
                const float4 alv = *(const float4*)(al1 + s * 4);
                float e0 = __expf(leaky(alv.x + arv.x));
                float e1 = __expf(leaky(alv.y + arv.y));
                float e2 = __expf(leaky(alv.z + arv.z));
                float e3 = __expf(leaky(alv.w + arv.w));
                s0 += e0; s1 += e1; s2 += e2; s3 += e3;
                __half2 h01 = __floats2half2_rn(e0, e1);
                __half2 h23 = __floats2half2_rn(e2, e3);
                *(uint2*)&s_alpha[w][g][e][0] =
                    make_uint2(*(unsigned*)&h01, *(unsigned*)&h23);
            }
        }
    } else {
        for (int e = li; e < deg; e += 8) {
            int s = sorted_src[rs + e];
            const float4 alv = *(const float4*)(al1 + s * 4);
            s0 += __expf(leaky(alv.x + arv.x));
            s1 += __expf(leaky(alv.y + arv.y));
            s2 += __expf(leaky(alv.z + arv.z));
            s3 += __expf(leaky(alv.w + arv.w));
        }
    }
#pragma unroll
    for (int off = 1; off < 8; off <<= 1) {
        s0 += __shfl_xor(s0, off, 64);
        s1 += __shfl_xor(s1, off, 64);
        s2 += __shfl_xor(s2, off, 64);
        s3 += __shfl_xor(s3, off, 64);
    }
    float inv0 = 0.f, inv1 = 0.f, inv2 = 0.f, inv3 = 0.f;
    if (deg > 0) {
        inv0 = 1.f / (s0 + 1e-16f); inv1 = 1.f / (s1 + 1e-16f);
        inv2 = 1.f / (s2 + 1e-16f); inv3 = 1.f / (s3 + 1e-16f);
    }
    float invh = (h == 0) ? inv0 : (h == 1) ? inv1 : (h == 2) ? inv2 : inv3;
    __half2 invh2 = __floats2half2_rn(invh, invh);
    // per-wave LDS write->read, in-order within wave: no barrier needed

    // ---- pass 2: gather-accumulate (f16 packed, 16B/lane), batch-8 ----
    __half2 a01 = __floats2half2_rn(0.f, 0.f);
    __half2 a23 = a01, a45 = a01, a67 = a01;
    float fb0=0.f, fb1=0.f, fb2=0.f, fb3=0.f, fb4=0.f, fb5=0.f, fb6=0.f, fb7=0.f;
    if (!big) {
        for (int i0 = 0; i0 < maxdeg; i0 += 8) {
            int myi = i0 + li;
            int mys = (myi < deg) ? sorted_src[rs + myi] : 0;
            int ss[8]; __half ah[8]; uint4 uu[8];
#pragma unroll
            for (int j = 0; j < 8; j++) {
                ss[j] = __shfl(mys, (g << 3) + j, 64);
                int i = i0 + j;
                ah[j] = (i < deg) ? s_alpha[w][g][i][h] : __float2half(0.f);
            }
#pragma unroll
            for (int j = 0; j < 8; j++) {
                int i = i0 + j;
                uu[j] = make_uint4(0u, 0u, 0u, 0u);
                if (i < deg) uu[j] = *(const uint4*)(xlin1h + (size_t)ss[j] * D1 + li * 8);
            }
#pragma unroll
            for (int j = 0; j < 8; j++) {
                __half2 a2 = __hmul2(__half2half2(ah[j]), invh2);
                a01 = __hfma2(a2, u2h2(uu[j].x), a01);
                a23 = __hfma2(a2, u2h2(uu[j].y), a23);
                a45 = __hfma2(a2, u2h2(uu[j].z), a45);
                a67 = __hfma2(a2, u2h2(uu[j].w), a67);
            }
        }
    } else {
        float arh = (h == 0) ? arv.x : (h == 1) ? arv.y : (h == 2) ? arv.z : arv.w;
        for (int i = 0; i < deg; i++) {
            int s = sorted_src[rs + i];
            const float4 alv = *(const float4*)(al1 + s * 4);
            float lv = (h == 0) ? alv.x : (h == 1) ? alv.y : (h == 2) ? alv.z : alv.w;
            float a = __expf(leaky(lv + arh)) * invh;
            uint4 u = *(const uint4*)(xlin1h + (size_t)s * D1 + li * 8);
            float2 x01 = __half22float2(u2h2(u.x));
            float2 x23 = __half22float2(u2h2(u.y));
            float2 x45 = __half22float2(u2h2(u.z));
            float2 x67 = __half22float2(u2h2(u.w));
            fb0 += a * x01.x; fb1 += a * x01.y; fb2 += a * x23.x; fb3 += a * x23.y;
            fb4 += a * x45.x; fb5 += a * x45.y; fb6 += a * x67.x; fb7 += a * x67.y;
        }
    }
    // ---- epilogue: + residual(f16), ELU -> h (f16), layer-2 dots ----
    float c0, c1, c2, c3, c4, c5, c6, c7;
    { float2 tv;
      tv = __half22float2(a01); c0 = tv.x + fb0; c1 = tv.y + fb1;
      tv = __half22float2(a23); c2 = tv.x + fb2; c3 = tv.y + fb3;
      tv = __half22float2(a45); c4 = tv.x + fb4; c5 = tv.y + fb5;
      tv = __half22float2(a67); c6 = tv.x + fb6; c7 = tv.y + fb7; }
    uint4 rres = *(const uint4*)(acc1h + (size_t)d * D1 + li * 8);
    { float2 tv;
      tv = __half22float2(u2h2(rres.x)); c0 += tv.x; c1 += tv.y;
      tv = __half22float2(u2h2(rres.y)); c2 += tv.x; c3 += tv.y;
      tv = __half22float2(u2h2(rres.z)); c4 += tv.x; c5 += tv.y;
      tv = __half22float2(u2h2(rres.w)); c6 += tv.x; c7 += tv.y; }
    c0 = c0 > 0.f ? c0 : (__expf(c0) - 1.f);
    c1 = c1 > 0.f ? c1 : (__expf(c1) - 1.f);
    c2 = c2 > 0.f ? c2 : (__expf(c2) - 1.f);
    c3 = c3 > 0.f ? c3 : (__expf(c3) - 1.f);
    c4 = c4 > 0.f ? c4 : (__expf(c4) - 1.f);
    c5 = c5 > 0.f ? c5 : (__expf(c5) - 1.f);
    c6 = c6 > 0.f ? c6 : (__expf(c6) - 1.f);
    c7 = c7 > 0.f ? c7 : (__expf(c7) - 1.f);
    __half2 o01 = __floats2half2_rn(c0, c1);
    __half2 o23 = __floats2half2_rn(c2, c3);
    __half2 o45 = __floats2half2_rn(c4, c5);
    __half2 o67 = __floats2half2_rn(c6, c7);
    uint4 hv = make_uint4(*(unsigned*)&o01, *(unsigned*)&o23,
                          *(unsigned*)&o45, *(unsigned*)&o67);
    *(uint4*)(hh + (size_t)d * D1 + li * 8) = hv;
    const float4 vla = *(const float4*)(vl + li * 8);
    const float4 vlb = *(const float4*)(vl + li * 8 + 4);
    const float4 vra = *(const float4*)(vr + li * 8);
    const float4 vrb = *(const float4*)(vr + li * 8 + 4);
    float pl = c0 * vla.x + c1 * vla.y + c2 * vla.z + c3 * vla.w
             + c4 * vlb.x + c5 * vlb.y + c6 * vlb.z + c7 * vlb.w;
    float pr = c0 * vra.x + c1 * vra.y + c2 * vra.z + c3 * vra.w
             + c4 * vrb.x + c5 * vrb.y + c6 * vrb.z + c7 * vrb.w;
#pragma unroll
    for (int off = 1; off < 8; off <<= 1) {
        pl += __shfl_xor(pl, off, 64);
        pr += __shfl_xor(pr, off, 64);
    }
    if (li == 0) { al2[d] = pl; ar2[d] = pr; }
}

// ====== Fused aggregation, layer 2 (H=1, C=64): gathers h, writes hsum bf16 ======
__global__ __launch_bounds__(256) void agg2_kernel(
        const int* __restrict__ sorted_src, const int* __restrict__ row_ptr,
        const int* __restrict__ counts,
        const float* __restrict__ al2, const float* __restrict__ ar2,
        const __half* __restrict__ hh,
        unsigned short* __restrict__ hsum) {
    __shared__ __half s_alpha[4][8][65];   // 4160 B
    __shared__ int    s_src[4][8][65];     // 8320 B
    int w = threadIdx.x >> 6, lane = threadIdx.x & 63;
    int g = lane >> 3, li = lane & 7;
    int d = blockIdx.x * 32 + w * 8 + g;
    int rs = row_ptr[d];
    int deg = counts[d];
    float ard = ar2[d];

    int maxdeg = deg;
    maxdeg = max(maxdeg, __shfl_xor(maxdeg, 8, 64));
    maxdeg = max(maxdeg, __shfl_xor(maxdeg, 16, 64));
    maxdeg = max(maxdeg, __shfl_xor(maxdeg, 32, 64));
    bool big = maxdeg > 64;

    float ssum = 0.f;
    if (!big) {
        for (int e = li; e < maxdeg; e += 8) {
            if (e < deg) {
                int s = sorted_src[rs + e];
                float ex = __expf(leaky(al2[s] + ard));
                ssum += ex;
                s_alpha[w][g][e] = __float2half(ex);
                s_src[w][g][e] = s;
            }
        }
    } else {
        for (int e = li; e < deg; e += 8) {
            int s = sorted_src[rs + e];
            ssum += __expf(leaky(al2[s] + ard));
        }
    }
#pragma unroll
    for (int off = 1; off < 8; off <<= 1) ssum += __shfl_xor(ssum, off, 64);
    float inv = (deg > 0) ? 1.f / (ssum + 1e-16f) : 0.f;
    __half2 inv2h = __floats2half2_rn(inv, inv);

    __half2 a01 = __floats2half2_rn(0.f, 0.f);
    __half2 a23 = a01, a45 = a01, a67 = a01;
    float fb0=0.f, fb1=0.f, fb2=0.f, fb3=0.f, fb4=0.f, fb5=0.f, fb6=0.f, fb7=0.f;
    if (!big) {
        for (int i0 = 0; i0 < maxdeg; i0 += 8) {
            int ss[8]; __half ah[8]; uint4 uu[8];
#pragma unroll
            for (int j = 0; j < 8; j++) {
                int i = i0 + j;
                bool v = i < deg;
                ss[j] = v ? s_src[w][g][i] : 0;
                ah[j] = v ? s_alpha[w][g][i] : __float2half(0.f);
            }
#pragma unroll
            for (int j = 0; j < 8; j++) {
                int i = i0 + j;
                uu[j] = make_uint4(0u, 0u, 0u, 0u);
                if (i < deg) uu[j] = *(const uint4*)(hh + (size_t)ss[j] * D1 + li * 8);
            }
#pragma unroll
            for (int j = 0; j < 8; j++) {
                __half2 a2 = __hmul2(__half2half2(ah[j]), inv2h);
                a01 = __hfma2(a2, u2h2(uu[j].x), a01);
                a23 = __hfma2(a2, u2h2(uu[j].y), a23);
                a45 = __hfma2(a2, u2h2(uu[j].z), a45);
                a67 = __hfma2(a2, u2h2(uu[j].w), a67);
            }
        }
    } else {
        for (int i = 0; i < deg; i++) {
            int s = sorted_src[rs + i];
            float a = __expf(leaky(al2[s] + ard)) * inv;
            uint4 u = *(const uint4*)(hh + (size_t)s * D1 + li * 8);
            float2 x01 = __half22float2(u2h2(u.x));
            float2 x23 = __half22float2(u2h2(u.y));
            float2 x45 = __half22float2(u2h2(u.z));
            float2 x67 = __half22float2(u2h2(u.w));
            fb0 += a * x01.x; fb1 += a * x01.y; fb2 += a * x23.x; fb3 += a * x23.y;
            fb4 += a * x45.x; fb5 += a * x45.y; fb6 += a * x67.x; fb7 += a * x67.y;
        }
    }
    // ---- epilogue: + own h[d] (layer-2 residual, pre-GEMM), write bf16 ----
    float c0, c1, c2, c3, c4, c5, c6, c7;
    { float2 tv;
      tv = __half22float2(a01); c0 = tv.x + fb0; c1 = tv.y + fb1;
      tv = __half22float2(a23); c2 = tv.x + fb2; c3 = tv.y + fb3;
      tv = __half22float2(a45); c4 = tv.x + fb4; c5 = tv.y + fb5;
      tv = __half22float2(a67); c6 = tv.x + fb6; c7 = tv.y + fb7; }
    uint4 own = *(const uint4*)(hh + (size_t)d * D1 + li * 8);
    { float2 tv;
      tv = __half22float2(u2h2(own.x)); c0 += tv.x; c1 += tv.y;
      tv = __half22float2(u2h2(own.y)); c2 += tv.x; c3 += tv.y;
      tv = __half22float2(u2h2(own.z)); c4 += tv.x; c5 += tv.y;
      tv = __half22float2(u2h2(own.w)); c6 += tv.x; c7 += tv.y; }
    union { unsigned short us[8]; uint4 u4; } hw;
    hw.us[0] = f2bf(c0); hw.us[1] = f2bf(c1); hw.us[2] = f2bf(c2); hw.us[3] = f2bf(c3);
    hw.us[4] = f2bf(c4); hw.us[5] = f2bf(c5); hw.us[6] = f2bf(c6); hw.us[7] = f2bf(c7);
    *(uint4*)(hsum + (size_t)d * D1 + li * 8) = hw.u4;
}

// ================= node3: final MFMA GEMM: out = hsum @ W2 + b2 =================
__global__ __launch_bounds__(256) void node3_kernel(
        const unsigned short* __restrict__ hsum,
        const unsigned short* __restrict__ W2tb,     // [64 cols][64 k] bf16
        const float* __restrict__ b2,
        float* __restrict__ out) {
    __shared__ char smemB[64 * LDB2];   // 9216 B
    int t = threadIdx.x;
    int base = blockIdx.x * 64;
    int wave = t >> 6, lane = t & 63;
    int quad = lane >> 4, li = lane & 15;
    int node = base + wave * 16 + li;

    uint4 breg[2];
#pragma unroll
    for (int s = 0; s < 2; s++) {
        int seg = s * 256 + t;                       // 512 = 64 rows * 8 segs
        breg[s] = *(const uint4*)(W2tb + (seg >> 3) * 64 + (seg & 7) * 8);
    }
    bf16x8 afr[2];
#pragma unroll
    for (int kc = 0; kc < 2; kc++)
#pragma unroll
        for (int i = 0; i < 8; i++) afr[kc][i] = 0;
    if (node < NN) {
        afr[0] = *(const bf16x8*)(hsum + (size_t)node * D1 + quad * 8);
        afr[1] = *(const bf16x8*)(hsum + (size_t)node * D1 + 32 + quad * 8);
    }
#pragma unroll
    for (int s = 0; s < 2; s++) {
        int seg = s * 256 + t;
        *(uint4*)(smemB + (seg >> 3) * LDB2 + (seg & 7) * 16) = breg[s];
    }
    __syncthreads();

    f32x4 accs[4];
#pragma unroll
    for (int nt = 0; nt < 4; nt++) accs[nt] = (f32x4){0.f, 0.f, 0.f, 0.f};
#pragma unroll
    for (int kc = 0; kc < 2; kc++) {
        const char* brow = smemB + kc * 64 + quad * 16;
#pragma unroll
        for (int nt = 0; nt < 4; nt++) {
            bf16x8 bfrag = *(const bf16x8*)(brow + (nt * 16 + li) * LDB2);
            accs[nt] = __builtin_amdgcn_mfma_f32_16x16x32_bf16(afr[kc], bfrag, accs[nt], 0, 0, 0);
        }
    }

    int m0 = base + wave * 16;
#pragma unroll
    for (int nt = 0; nt < 4; nt++) {
        int col = nt * 16 + li;
        float bv = b2[col];
#pragma unroll
        for (int j = 0; j < 4; j++) {
            int nd = m0 + quad * 4 + j;
            if (nd < NN) out[(size_t)nd * OUT_DIM + col] = accs[nt][j] + bv;
        }
    }
}

extern "C" void kernel_launch(void* const* d_in, const int* in_sizes, int n_in,
                              void* d_out, int out_size, void* d_ws, size_t ws_size,
                              hipStream_t stream) {
    const float* x     = (const float*)d_in[0];
    const int*   eidx  = (const int*)d_in[1];
    const float* W1    = (const float*)d_in[2];
    const float* attl1 = (const float*)d_in[3];
    const float* attr1 = (const float*)d_in[4];
    const float* resW1 = (const float*)d_in[5];
    const float* b1    = (const float*)d_in[6];
    const float* W2    = (const float*)d_in[7];
    const float* attl2 = (const float*)d_in[8];
    const float* attr2 = (const float*)d_in[9];
    const float* b2    = (const float*)d_in[10];

    const int* src = eidx;
    const int* dst = eidx + EE;

    // workspace layout
    __half* xlin1h = (__half*)d_ws;                            // N*64 f16
    __half* acc1h  = xlin1h + (size_t)NN * D1;                 // N*64 f16 residual
    __half* hh     = acc1h + (size_t)NN * D1;                  // N*64 f16 h
    unsigned short* hsum = (unsigned short*)(hh + (size_t)NN * D1);  // N*64 bf16
    float* al1   = (float*)(hsum + (size_t)NN * D1);           // N*4
    float* ar1   = al1 + (size_t)NN * HEADS;                   // N*4
    float* al2   = ar1 + (size_t)NN * HEADS;                   // N
    float* ar2   = al2 + NN;                                   // N
    float* vl    = ar2 + NN;                                   // 64
    float* vr    = vl + D1;                                    // 64
    unsigned short* Wtb  = (unsigned short*)(vr + D1);         // 144*128 bf16
    unsigned short* W2tb = Wtb + W1COLS * 128;                 // 64*64 bf16
    int* counts        = (int*)(W2tb + 64 * 64);               // N
    int* row_ptr       = counts + NN;                          // N
    int* bucket_cursor = row_ptr + NN;                         // 512
    int* sorted_src    = bucket_cursor + 512;                  // NB*BCAP = 2001920
    unsigned* binned = (unsigned*)d_out;    // NB*BCAP u32 = 8 MB; dead after binB

    float* out = (float*)d_out;

    // ---- prep + CSR build (binA fused with node1) ----
    prep_kernel<<<3, 512, 0, stream>>>(bucket_cursor, W1, resW1, W2,
                                       attl1, attr1, attl2, attr2,
                                       Wtb, W2tb, vl, vr);
    fusedA_kernel<<<BINA_BLOCKS + NODE_BLOCKS, 256, 0, stream>>>(
        src, dst, bucket_cursor, binned,
        x, Wtb, b1, xlin1h, acc1h, al1, ar1);
    binB_kernel<<<NB, 256, 0, stream>>>(binned, bucket_cursor,
                                        row_ptr, counts, sorted_src);

    // ---- layer 1 aggregation (+ residual + ELU + layer-2 dots) ----
    agg1_kernel<<<AGG_BLOCKS, 256, 0, stream>>>(sorted_src, row_ptr, counts,
                                                al1, ar1, xlin1h, acc1h, hh,
                                                vl, vr, al2, ar2);

    // ---- layer 2: aggregate h, then single GEMM ----
    agg2_kernel<<<AGG_BLOCKS, 256, 0, stream>>>(sorted_src, row_ptr, counts,
                                                al2, ar2, hh, hsum);
    node3_kernel<<<NODE_BLOCKS, 256, 0, stream>>>(hsum, W2tb, b2, out);
}

// Round 12
// 241.512 us; speedup vs baseline: 1.2009x; 1.0226x over previous
//
#include <hip/hip_runtime.h>
#include <hip/hip_bf16.h>
#include <hip/hip_fp16.h>
#include <math.h>

// AGDN: 2-layer graph attention. N=100000, E=1600000, IN=128, HID=16, HEADS=4, OUT=64.
// Best-of composition (R12): fusedA = single-stage B-tile + SEPI=72 epilogue (R7's
// 42.8us variant); agg1/agg2 = dynamic pass-1, shfl src-broadcast (R11's 42.4us);
// binA direct scatter; layer-2 GEMM commuted past aggregation.
// NOTE: __launch_bounds__ 2nd arg is min waves/EU (SIMD), NOT blocks/CU — (256,7)
// capped VGPR at 64 and spilled (R9 regression). Keep (256,4).
#define NN 100000
#define EE 1600000
#define IN_DIM 128
#define HID 16
#define HEADS 4
#define D1 64
#define OUT_DIM 64
#define SLOPE 0.2f

#define NB 391                 // ceil(N/256) buckets of 256 nodes
#define BCAP 5120              // bucket capacity (mean 4092, +16 sigma)
#define BINA_CHUNK 4096
#define BINA_BLOCKS ((EE + BINA_CHUNK - 1) / BINA_CHUNK)   // 391
#define NODE_BLOCKS ((NN + 63) / 64)                        // 1563
#define AGG_BLOCKS (NN / 32)                                // 3125 (exact)

#define W1COLS 144             // 64 xlin | 64 residual | 4 al | 4 ar | 8 pad
#define LDB1 272               // node1 B row stride: 128 bf16 = 256B + 16B pad
#define LDB2 144               // node3: 64 bf16 = 128B + 16B pad
#define SEPI 72                // node1 epilogue stage stride (f16): 144B rows

typedef __attribute__((ext_vector_type(8))) short bf16x8;
typedef __attribute__((ext_vector_type(4))) float f32x4;

__device__ __forceinline__ float leaky(float v) { return v > 0.f ? v : SLOPE * v; }
__device__ __forceinline__ unsigned short f2bf(float f) {
    __hip_bfloat16 h = __float2bfloat16(f);
    return *(unsigned short*)&h;
}
__device__ __forceinline__ __half2 u2h2(unsigned u) {
    union { unsigned u; __half2 h; } c; c.u = u; return c.h;
}
__device__ __forceinline__ bf16x8 pack8(float4 a, float4 b) {
    bf16x8 r;
    r[0] = (short)f2bf(a.x); r[1] = (short)f2bf(a.y);
    r[2] = (short)f2bf(a.z); r[3] = (short)f2bf(a.w);
    r[4] = (short)f2bf(b.x); r[5] = (short)f2bf(b.y);
    r[6] = (short)f2bf(b.z); r[7] = (short)f2bf(b.w);
    return r;
}

// ====== Prep: bucket cursors (b0) + W1/resW/att-fold bf16 (b1) + W2 (b2) ====
__global__ void prep_kernel(int* __restrict__ bucket_cursor,
                            const float* __restrict__ W1,
                            const float* __restrict__ resW,
                            const float* __restrict__ W2,
                            const float* __restrict__ attl1,
                            const float* __restrict__ attr1,
                            const float* __restrict__ attl2,
                            const float* __restrict__ attr2,
                            unsigned short* __restrict__ Wtb,
                            unsigned short* __restrict__ W2tb,
                            float* __restrict__ vl, float* __restrict__ vr) {
    int t = threadIdx.x;
    if (blockIdx.x == 0) {
        if (t < NB) bucket_cursor[t] = t * BCAP;
    } else if (blockIdx.x == 1) {
        for (int idx = t; idx < W1COLS * 128; idx += 512) {
            int col = idx >> 7, k = idx & 127;
            float w = 0.f;
            if (col < 64) {
                w = W1[k * 64 + col];
            } else if (col < 128) {
                w = resW[k * 64 + (col - 64)];
            } else if (col < 132) {
                int hh = col - 128;
                for (int c = 0; c < HID; c++)
                    w += W1[k * 64 + hh * HID + c] * attl1[hh * HID + c];
            } else if (col < 136) {
                int hh = col - 132;
                for (int c = 0; c < HID; c++)
                    w += W1[k * 64 + hh * HID + c] * attr1[hh * HID + c];
            }
            Wtb[idx] = f2bf(w);
        }
    } else {
        for (int idx = t; idx < 64 * 64; idx += 512) {
            int col = idx >> 6, k = idx & 63;
            W2tb[idx] = f2bf(W2[k * 64 + col]);
        }
        if (t < D1) {
            float a = 0.f, b = 0.f;
            for (int o = 0; o < OUT_DIM; o++) {
                float w = W2[t * OUT_DIM + o];
                a += w * attl2[o];
                b += w * attr2[o];
            }
            vl[t] = a; vr[t] = b;
        }
    }
}

// ============ fusedA: grid union of binA (multisplit) and node1 (MFMA) ============
__device__ __forceinline__ void binA_body(char* smem, int bid,
        const int* __restrict__ src, const int* __restrict__ dst,
        int* __restrict__ bucket_cursor, unsigned* __restrict__ binned) {
    int* lhist = (int*)smem;          // 512 ints
    int* lcur  = lhist + 512;         // 512 ints
    int* gbase = lcur + 512;          // 512 ints (6KB total)
    int t = threadIdx.x;
    lhist[t] = 0; lhist[t + 256] = 0;
    lcur[t] = 0;  lcur[t + 256] = 0;
    __syncthreads();
    int e0 = bid * BINA_CHUNK;
    unsigned pk[16];
    unsigned short bk[16];
#pragma unroll
    for (int i = 0; i < 16; i++) {
        int e = e0 + t + i * 256;
        if (e < EE) {
            int d = dst[e], s = src[e];
            int b = d >> 8;
            pk[i] = ((unsigned)(d & 255) << 24) | (unsigned)s;
            bk[i] = (unsigned short)b;
            atomicAdd(&lhist[b], 1);
        } else bk[i] = 0xFFFFu;
    }
    __syncthreads();
    int c1 = lhist[t], c2 = lhist[t + 256];
    if (c1) gbase[t] = atomicAdd(&bucket_cursor[t], c1);
    if (c2) gbase[t + 256] = atomicAdd(&bucket_cursor[t + 256], c2);
    __syncthreads();
#pragma unroll
    for (int i = 0; i < 16; i++) {
        if (bk[i] != 0xFFFFu) {
            int b = bk[i];
            int pos = atomicAdd(&lcur[b], 1);
            int idx = gbase[b] + pos;
            if (idx < (b + 1) * BCAP) binned[idx] = pk[i];  // overflow guard (~never)
        }
    }
}

__device__ __forceinline__ void node1_body(char* smemB, int bid,
        const float* __restrict__ x, const unsigned short* __restrict__ Wtb,
        const float* __restrict__ b1, __half* __restrict__ xlin1h,
        __half* __restrict__ acc1h, float* __restrict__ al1,
        float* __restrict__ ar1) {
    int t = threadIdx.x;
    int base = bid * 64;
    int wave = t >> 6, lane = t & 63;
    int quad = lane >> 4, li = lane & 15;
    int node = base + wave * 16 + li;

    uint4 breg[9];
#pragma unroll
    for (int s = 0; s < 9; s++) {
        int seg = s * 256 + t;                       // 2304 = 144 rows * 16 segs
        breg[s] = *(const uint4*)(Wtb + (seg >> 4) * 128 + (seg & 15) * 8);
    }
    float4 xreg[8];
#pragma unroll
    for (int i = 0; i < 8; i++) xreg[i] = make_float4(0.f, 0.f, 0.f, 0.f);
    if (node < NN) {
        const float* xp = x + (size_t)node * IN_DIM + quad * 8;
#pragma unroll
        for (int kc = 0; kc < 4; kc++) {
            xreg[kc * 2]     = *(const float4*)(xp + kc * 32);
            xreg[kc * 2 + 1] = *(const float4*)(xp + kc * 32 + 4);
        }
    }
#pragma unroll
    for (int s = 0; s < 9; s++) {
        int seg = s * 256 + t;
        *(uint4*)(smemB + (seg >> 4) * LDB1 + (seg & 15) * 16) = breg[s];
    }
    __syncthreads();

    f32x4 accs[9];
#pragma unroll
    for (int nt = 0; nt < 9; nt++) accs[nt] = (f32x4){0.f, 0.f, 0.f, 0.f};
#pragma unroll
    for (int kc = 0; kc < 4; kc++) {
        bf16x8 afrag = pack8(xreg[kc * 2], xreg[kc * 2 + 1]);
        const char* brow = smemB + kc * 64 + quad * 16;
#pragma unroll
        for (int nt = 0; nt < 9; nt++) {
            bf16x8 bfrag = *(const bf16x8*)(brow + (nt * 16 + li) * LDB1);
            accs[nt] = __builtin_amdgcn_mfma_f32_16x16x32_bf16(afrag, bfrag, accs[nt], 0, 0, 0);
        }
    }

    // ---- epilogue: stage f16 in (now-dead) smemB at stride 72 (no conflicts) ----
    __syncthreads();   // all B-tile reads complete before overwrite
    __half* sx = (__half*)smemB;          // [64][72] f16 xlin  (9216B)
    __half* sa = sx + 64 * SEPI;          // [64][72] f16 acc   (9216B)
#pragma unroll
    for (int nt = 0; nt < 4; nt++) {
#pragma unroll
        for (int j = 0; j < 4; j++) {
            int rl = wave * 16 + quad * 4 + j;
            sx[rl * SEPI + nt * 16 + li] = __float2half(accs[nt][j]);
        }
    }
#pragma unroll
    for (int nt = 4; nt < 8; nt++) {
        int col = (nt - 4) * 16 + li;
        float bv = b1[col];
#pragma unroll
        for (int j = 0; j < 4; j++) {
            int rl = wave * 16 + quad * 4 + j;
            sa[rl * SEPI + col] = __float2half(accs[nt][j] + bv);
        }
    }
    __syncthreads();
    for (int i = t; i < 512; i += 256) {
        int row = i >> 3, seg = i & 7;
        int nd = base + row;
        if (nd < NN) {
            *(uint4*)(xlin1h + (size_t)nd * D1 + seg * 8) =
                *(const uint4*)(sx + row * SEPI + seg * 8);
            *(uint4*)(acc1h + (size_t)nd * D1 + seg * 8) =
                *(const uint4*)(sa + row * SEPI + seg * 8);
        }
    }
    int m0 = base + wave * 16;
#pragma unroll
    for (int j = 0; j < 4; j++) {
        int nd = m0 + quad * 4 + j;
        if (nd < NN) {
            if (li < 4) al1[nd * HEADS + li] = accs[8][j];
            else if (li < 8) ar1[nd * HEADS + (li - 4)] = accs[8][j];
        }
    }
}

__global__ __launch_bounds__(256, 4) void fusedA_kernel(
        const int* __restrict__ src, const int* __restrict__ dst,
        int* __restrict__ bucket_cursor, unsigned* __restrict__ binned,
        const float* __restrict__ x, const unsigned short* __restrict__ Wtb,
        const float* __restrict__ b1, __half* __restrict__ xlin1h,
        __half* __restrict__ acc1h, float* __restrict__ al1,
        float* __restrict__ ar1) {
    __shared__ __align__(16) char smem[W1COLS * LDB1];   // 39168 B (binA uses 6KB)
    if (blockIdx.x < BINA_BLOCKS)
        binA_body(smem, blockIdx.x, src, dst, bucket_cursor, binned);
    else
        node1_body(smem, blockIdx.x - BINA_BLOCKS, x, Wtb, b1, xlin1h, acc1h, al1, ar1);
}

// ================= binB: per-bucket counting sort (shfl scan) =================
__global__ __launch_bounds__(256) void binB_kernel(const unsigned* __restrict__ binned,
                                                   const int* __restrict__ bucket_cursor,
                                                   int* __restrict__ row_ptr,
                                                   int* __restrict__ counts,
                                                   int* __restrict__ sorted_src) {
    __shared__ int lcount[256], lrow[256], lcur[256];
    __shared__ int wtot[4];
    int b = blockIdx.x, t = threadIdx.x;
    int start = b * BCAP;
    int cnt = bucket_cursor[b] - start;
    if (cnt > BCAP) cnt = BCAP;
    lcount[t] = 0;
    __syncthreads();
    for (int i = t; i < cnt; i += 256) {
        atomicAdd(&lcount[binned[start + i] >> 24], 1);
    }
    __syncthreads();
    int v = lcount[t];
    int lane = t & 63, wv = t >> 6;
    int inc = v;
#pragma unroll
    for (int off = 1; off < 64; off <<= 1) {
        int n = __shfl_up(inc, off, 64);
        if (lane >= off) inc += n;
    }
    if (lane == 63) wtot[wv] = inc;
    __syncthreads();
    int wbase = 0;
#pragma unroll
    for (int i = 0; i < 4; i++) if (i < wv) wbase += wtot[i];
    int ex = wbase + inc - v;
    lrow[t] = ex;
    lcur[t] = 0;
    int node = (b << 8) + t;
    if (node < NN) {
        row_ptr[node] = start + ex;
        counts[node] = v;
    }
    __syncthreads();
    for (int i = t; i < cnt; i += 256) {
        unsigned p = binned[start + i];
        int low = p >> 24;
        int pos = atomicAdd(&lcur[low], 1);
        sorted_src[start + lrow[low] + pos] = (int)(p & 0xFFFFFFu);
    }
}

// ====== Fused aggregation, layer 1 (H=4,C=16) + residual + ELU + L2 dots ======
// 8 dst nodes per wave: g=lane>>3 node, li=lane&7 owns channels li*8..+7 (head li>>1).
// pass-2 batch-8; src indices re-read from L1-hot sorted_src + shfl broadcast.
__global__ __launch_bounds__(256) void agg1_kernel(
        const int* __restrict__ sorted_src, const int* __restrict__ row_ptr,
        const int* __restrict__ counts,
        const float* __restrict__ al1, const float* __restrict__ ar1,
        const __half* __restrict__ xlin1h, const __half* __restrict__ acc1h,
        __half* __restrict__ hh,
        const float* __restrict__ vl, const float* __restrict__ vr,
        float* __restrict__ al2, float* __restrict__ ar2) {
    __shared__ __half s_alpha[4][8][65][4];   // 16640 B
    int w = threadIdx.x >> 6, lane = threadIdx.x & 63;
    int g = lane >> 3, li = lane & 7;
    int d = blockIdx.x * 32 + w * 8 + g;      // AGG_BLOCKS*32 == NN exactly
    int rs = row_ptr[d];
    int deg = counts[d];
    const float4 arv = *(const float4*)(ar1 + d * 4);
    int h = li >> 1;

    int maxdeg = deg;
    maxdeg = max(maxdeg, __shfl_xor(maxdeg, 8, 64));
    maxdeg = max(maxdeg, __shfl_xor(maxdeg, 16, 64));
    maxdeg = max(maxdeg, __shfl_xor(maxdeg, 32, 64));
    bool big = maxdeg > 64;   // wave-uniform, ~never

    // ---- pass 1: raw exps (logits bounded) to LDS, per-group sums ----
    float s0 = 0.f, s1 = 0.f, s2 = 0.f, s3 = 0.f;
    if (!big) {
        for (int e = li; e < maxdeg; e += 8) {
            if (e < deg) {
                int s = sorted_src[rs + e];
                const float4 alv = *(const float4*)(al1 + s * 4);
                float e0 = __expf(leaky(alv.x + arv.x));
                float e1 = __expf(leaky(alv.y + arv.y));
                float e2 = __expf(leaky(alv.z + arv.z));
                float e3 = __expf(leaky(alv.w + arv.w));
                s0 += e0; s1 += e1; s2 += e2; s3 += e3;
                __half2 h01 = __floats2half2_rn(e0, e1);
                __half2 h23 = __floats2half2_rn(e2, e3);
                *(uint2*)&s_alpha[w][g][e][0] =
                    make_uint2(*(unsigned*)&h01, *(unsigned*)&h23);
            }
        }
    } else {
        for (int e = li; e < deg; e += 8) {
            int s = sorted_src[rs + e];
            const float4 alv = *(const float4*)(al1 + s * 4);
            s0 += __expf(leaky(alv.x + arv.x));
            s1 += __expf(leaky(alv.y + arv.y));
            s2 += __expf(leaky(alv.z + arv.z));
            s3 += __expf(leaky(alv.w + arv.w));
        }
    }
#pragma unroll
    for (int off = 1; off < 8; off <<= 1) {
        s0 += __shfl_xor(s0, off, 64);
        s1 += __shfl_xor(s1, off, 64);
        s2 += __shfl_xor(s2, off, 64);
        s3 += __shfl_xor(s3, off, 64);
    }
    float inv0 = 0.f, inv1 = 0.f, inv2 = 0.f, inv3 = 0.f;
    if (deg > 0) {
        inv0 = 1.f / (s0 + 1e-16f); inv1 = 1.f / (s1 + 1e-16f);
        inv2 = 1.f / (s2 + 1e-16f); inv3 = 1.f / (s3 + 1e-16f);
    }
    float invh = (h == 0) ? inv0 : (h == 1) ? inv1 : (h == 2) ? inv2 : inv3;
    __half2 invh2 = __floats2half2_rn(invh, invh);
    // per-wave LDS write->read, in-order within wave: no barrier needed

    // ---- pass 2: gather-accumulate (f16 packed, 16B/lane), batch-8 ----
    __half2 a01 = __floats2half2_rn(0.f, 0.f);
    __half2 a23 = a01, a45 = a01, a67 = a01;
    float fb0=0.f, fb1=0.f, fb2=0.f, fb3=0.f, fb4=0.f, fb5=0.f, fb6=0.f, fb7=0.f;
    if (!big) {
        for (int i0 = 0; i0 < maxdeg; i0 += 8) {
            int myi = i0 + li;
            int mys = (myi < deg) ? sorted_src[rs + myi] : 0;
            int ss[8]; __half ah[8]; uint4 uu[8];
#pragma unroll
            for (int j = 0; j < 8; j++) {
                ss[j] = __shfl(mys, (g << 3) + j, 64);
                int i = i0 + j;
                ah[j] = (i < deg) ? s_alpha[w][g][i][h] : __float2half(0.f);
            }
#pragma unroll
            for (int j = 0; j < 8; j++) {
                int i = i0 + j;
                uu[j] = make_uint4(0u, 0u, 0u, 0u);
                if (i < deg) uu[j] = *(const uint4*)(xlin1h + (size_t)ss[j] * D1 + li * 8);
            }
#pragma unroll
            for (int j = 0; j < 8; j++) {
                __half2 a2 = __hmul2(__half2half2(ah[j]), invh2);
                a01 = __hfma2(a2, u2h2(uu[j].x), a01);
                a23 = __hfma2(a2, u2h2(uu[j].y), a23);
                a45 = __hfma2(a2, u2h2(uu[j].z), a45);
                a67 = __hfma2(a2, u2h2(uu[j].w), a67);
            }
        }
    } else {
        float arh = (h == 0) ? arv.x : (h == 1) ? arv.y : (h == 2) ? arv.z : arv.w;
        for (int i = 0; i < deg; i++) {
            int s = sorted_src[rs + i];
            const float4 alv = *(const float4*)(al1 + s * 4);
            float lv = (h == 0) ? alv.x : (h == 1) ? alv.y : (h == 2) ? alv.z : alv.w;
            float a = __expf(leaky(lv + arh)) * invh;
            uint4 u = *(const uint4*)(xlin1h + (size_t)s * D1 + li * 8);
            float2 x01 = __half22float2(u2h2(u.x));
            float2 x23 = __half22float2(u2h2(u.y));
            float2 x45 = __half22float2(u2h2(u.z));
            float2 x67 = __half22float2(u2h2(u.w));
            fb0 += a * x01.x; fb1 += a * x01.y; fb2 += a * x23.x; fb3 += a * x23.y;
            fb4 += a * x45.x; fb5 += a * x45.y; fb6 += a * x67.x; fb7 += a * x67.y;
        }
    }
    // ---- epilogue: + residual(f16), ELU -> h (f16), layer-2 dots ----
    float c0, c1, c2, c3, c4, c5, c6, c7;
    { float2 tv;
      tv = __half22float2(a01); c0 = tv.x + fb0; c1 = tv.y + fb1;
      tv = __half22float2(a23); c2 = tv.x + fb2; c3 = tv.y + fb3;
      tv = __half22float2(a45); c4 = tv.x + fb4; c5 = tv.y + fb5;
      tv = __half22float2(a67); c6 = tv.x + fb6; c7 = tv.y + fb7; }
    uint4 rres = *(const uint4*)(acc1h + (size_t)d * D1 + li * 8);
    { float2 tv;
      tv = __half22float2(u2h2(rres.x)); c0 += tv.x; c1 += tv.y;
      tv = __half22float2(u2h2(rres.y)); c2 += tv.x; c3 += tv.y;
      tv = __half22float2(u2h2(rres.z)); c4 += tv.x; c5 += tv.y;
      tv = __half22float2(u2h2(rres.w)); c6 += tv.x; c7 += tv.y; }
    c0 = c0 > 0.f ? c0 : (__expf(c0) - 1.f);
    c1 = c1 > 0.f ? c1 : (__expf(c1) - 1.f);
    c2 = c2 > 0.f ? c2 : (__expf(c2) - 1.f);
    c3 = c3 > 0.f ? c3 : (__expf(c3) - 1.f);
    c4 = c4 > 0.f ? c4 : (__expf(c4) - 1.f);
    c5 = c5 > 0.f ? c5 : (__expf(c5) - 1.f);
    c6 = c6 > 0.f ? c6 : (__expf(c6) - 1.f);
    c7 = c7 > 0.f ? c7 : (__expf(c7) - 1.f);
    __half2 o01 = __floats2half2_rn(c0, c1);
    __half2 o23 = __floats2half2_rn(c2, c3);
    __half2 o45 = __floats2half2_rn(c4, c5);
    __half2 o67 = __floats2half2_rn(c6, c7);
    uint4 hv = make_uint4(*(unsigned*)&o01, *(unsigned*)&o23,
                          *(unsigned*)&o45, *(unsigned*)&o67);
    *(uint4*)(hh + (size_t)d * D1 + li * 8) = hv;
    const float4 vla = *(const float4*)(vl + li * 8);
    const float4 vlb = *(const float4*)(vl + li * 8 + 4);
    const float4 vra = *(const float4*)(vr + li * 8);
    const float4 vrb = *(const float4*)(vr + li * 8 + 4);
    float pl = c0 * vla.x + c1 * vla.y + c2 * vla.z + c3 * vla.w
             + c4 * vlb.x + c5 * vlb.y + c6 * vlb.z + c7 * vlb.w;
    float pr = c0 * vra.x + c1 * vra.y + c2 * vra.z + c3 * vra.w
             + c4 * vrb.x + c5 * vrb.y + c6 * vrb.z + c7 * vrb.w;
#pragma unroll
    for (int off = 1; off < 8; off <<= 1) {
        pl += __shfl_xor(pl, off, 64);
        pr += __shfl_xor(pr, off, 64);
    }
    if (li == 0) { al2[d] = pl; ar2[d] = pr; }
}

// ====== Fused aggregation, layer 2 (H=1, C=64): gathers h, writes hsum bf16 ======
__global__ __launch_bounds__(256) void agg2_kernel(
        const int* __restrict__ sorted_src, const int* __restrict__ row_ptr,
        const int* __restrict__ counts,
        const float* __restrict__ al2, const float* __restrict__ ar2,
        const __half* __restrict__ hh,
        unsigned short* __restrict__ hsum) {
    __shared__ __half s_alpha[4][8][65];   // 4160 B
    __shared__ int    s_src[4][8][65];     // 8320 B
    int w = threadIdx.x >> 6, lane = threadIdx.x & 63;
    int g = lane >> 3, li = lane & 7;
    int d = blockIdx.x * 32 + w * 8 + g;
    int rs = row_ptr[d];
    int deg = counts[d];
    float ard = ar2[d];

    int maxdeg = deg;
    maxdeg = max(maxdeg, __shfl_xor(maxdeg, 8, 64));
    maxdeg = max(maxdeg, __shfl_xor(maxdeg, 16, 64));
    maxdeg = max(maxdeg, __shfl_xor(maxdeg, 32, 64));
    bool big = maxdeg > 64;

    float ssum = 0.f;
    if (!big) {
        for (int e = li; e < maxdeg; e += 8) {
            if (e < deg) {
                int s = sorted_src[rs + e];
                float ex = __expf(leaky(al2[s] + ard));
                ssum += ex;
                s_alpha[w][g][e] = __float2half(ex);
                s_src[w][g][e] = s;
            }
        }
    } else {
        for (int e = li; e < deg; e += 8) {
            int s = sorted_src[rs + e];
            ssum += __expf(leaky(al2[s] + ard));
        }
    }
#pragma unroll
    for (int off = 1; off < 8; off <<= 1) ssum += __shfl_xor(ssum, off, 64);
    float inv = (deg > 0) ? 1.f / (ssum + 1e-16f) : 0.f;
    __half2 inv2h = __floats2half2_rn(inv, inv);

    __half2 a01 = __floats2half2_rn(0.f, 0.f);
    __half2 a23 = a01, a45 = a01, a67 = a01;
    float fb0=0.f, fb1=0.f, fb2=0.f, fb3=0.f, fb4=0.f, fb5=0.f, fb6=0.f, fb7=0.f;
    if (!big) {
        for (int i0 = 0; i0 < maxdeg; i0 += 8) {
            int ss[8]; __half ah[8]; uint4 uu[8];
#pragma unroll
            for (int j = 0; j < 8; j++) {
                int i = i0 + j;
                bool v = i < deg;
                ss[j] = v ? s_src[w][g][i] : 0;
                ah[j] = v ? s_alpha[w][g][i] : __float2half(0.f);
            }
#pragma unroll
            for (int j = 0; j < 8; j++) {
                int i = i0 + j;
                uu[j] = make_uint4(0u, 0u, 0u, 0u);
                if (i < deg) uu[j] = *(const uint4*)(hh + (size_t)ss[j] * D1 + li * 8);
            }
#pragma unroll
            for (int j = 0; j < 8; j++) {
                __half2 a2 = __hmul2(__half2half2(ah[j]), inv2h);
                a01 = __hfma2(a2, u2h2(uu[j].x), a01);
                a23 = __hfma2(a2, u2h2(uu[j].y), a23);
                a45 = __hfma2(a2, u2h2(uu[j].z), a45);
                a67 = __hfma2(a2, u2h2(uu[j].w), a67);
            }
        }
    } else {
        for (int i = 0; i < deg; i++) {
            int s = sorted_src[rs + i];
            float a = __expf(leaky(al2[s] + ard)) * inv;
            uint4 u = *(const uint4*)(hh + (size_t)s * D1 + li * 8);
            float2 x01 = __half22float2(u2h2(u.x));
            float2 x23 = __half22float2(u2h2(u.y));
            float2 x45 = __half22float2(u2h2(u.z));
            float2 x67 = __half22float2(u2h2(u.w));
            fb0 += a * x01.x; fb1 += a * x01.y; fb2 += a * x23.x; fb3 += a * x23.y;
            fb4 += a * x45.x; fb5 += a * x45.y; fb6 += a * x67.x; fb7 += a * x67.y;
        }
    }
    // ---- epilogue: + own h[d] (layer-2 residual, pre-GEMM), write bf16 ----
    float c0, c1, c2, c3, c4, c5, c6, c7;
    { float2 tv;
      tv = __half22float2(a01); c0 = tv.x + fb0; c1 = tv.y + fb1;
      tv = __half22float2(a23); c2 = tv.x + fb2; c3 = tv.y + fb3;
      tv = __half22float2(a45); c4 = tv.x + fb4; c5 = tv.y + fb5;
      tv = __half22float2(a67); c6 = tv.x + fb6; c7 = tv.y + fb7; }
    uint4 own = *(const uint4*)(hh + (size_t)d * D1 + li * 8);
    { float2 tv;
      tv = __half22float2(u2h2(own.x)); c0 += tv.x; c1 += tv.y;
      tv = __half22float2(u2h2(own.y)); c2 += tv.x; c3 += tv.y;
      tv = __half22float2(u2h2(own.z)); c4 += tv.x; c5 += tv.y;
      tv = __half22float2(u2h2(own.w)); c6 += tv.x; c7 += tv.y; }
    union { unsigned short us[8]; uint4 u4; } hw;
    hw.us[0] = f2bf(c0); hw.us[1] = f2bf(c1); hw.us[2] = f2bf(c2); hw.us[3] = f2bf(c3);
    hw.us[4] = f2bf(c4); hw.us[5] = f2bf(c5); hw.us[6] = f2bf(c6); hw.us[7] = f2bf(c7);
    *(uint4*)(hsum + (size_t)d * D1 + li * 8) = hw.u4;
}

// ================= node3: final MFMA GEMM: out = hsum @ W2 + b2 =================
__global__ __launch_bounds__(256) void node3_kernel(
        const unsigned short* __restrict__ hsum,
        const unsigned short* __restrict__ W2tb,     // [64 cols][64 k] bf16
        const float* __restrict__ b2,
        float* __restrict__ out) {
    __shared__ char smemB[64 * LDB2];   // 9216 B
    int t = threadIdx.x;
    int base = blockIdx.x * 64;
    int wave = t >> 6, lane = t & 63;
    int quad = lane >> 4, li = lane & 15;
    int node = base + wave * 16 + li;

    uint4 breg[2];
#pragma unroll
    for (int s = 0; s < 2; s++) {
        int seg = s * 256 + t;                       // 512 = 64 rows * 8 segs
        breg[s] = *(const uint4*)(W2tb + (seg >> 3) * 64 + (seg & 7) * 8);
    }
    bf16x8 afr[2];
#pragma unroll
    for (int kc = 0; kc < 2; kc++)
#pragma unroll
        for (int i = 0; i < 8; i++) afr[kc][i] = 0;
    if (node < NN) {
        afr[0] = *(const bf16x8*)(hsum + (size_t)node * D1 + quad * 8);
        afr[1] = *(const bf16x8*)(hsum + (size_t)node * D1 + 32 + quad * 8);
    }
#pragma unroll
    for (int s = 0; s < 2; s++) {
        int seg = s * 256 + t;
        *(uint4*)(smemB + (seg >> 3) * LDB2 + (seg & 7) * 16) = breg[s];
    }
    __syncthreads();

    f32x4 accs[4];
#pragma unroll
    for (int nt = 0; nt < 4; nt++) accs[nt] = (f32x4){0.f, 0.f, 0.f, 0.f};
#pragma unroll
    for (int kc = 0; kc < 2; kc++) {
        const char* brow = smemB + kc * 64 + quad * 16;
#pragma unroll
        for (int nt = 0; nt < 4; nt++) {
            bf16x8 bfrag = *(const bf16x8*)(brow + (nt * 16 + li) * LDB2);
            accs[nt] = __builtin_amdgcn_mfma_f32_16x16x32_bf16(afr[kc], bfrag, accs[nt], 0, 0, 0);
        }
    }

    int m0 = base + wave * 16;
#pragma unroll
    for (int nt = 0; nt < 4; nt++) {
        int col = nt * 16 + li;
        float bv = b2[col];
#pragma unroll
        for (int j = 0; j < 4; j++) {
            int nd = m0 + quad * 4 + j;
            if (nd < NN) out[(size_t)nd * OUT_DIM + col] = accs[nt][j] + bv;
        }
    }
}

extern "C" void kernel_launch(void* const* d_in, const int* in_sizes, int n_in,
                              void* d_out, int out_size, void* d_ws, size_t ws_size,
                              hipStream_t stream) {
    const float* x     = (const float*)d_in[0];
    const int*   eidx  = (const int*)d_in[1];
    const float* W1    = (const float*)d_in[2];
    const float* attl1 = (const float*)d_in[3];
    const float* attr1 = (const float*)d_in[4];
    const float* resW1 = (const float*)d_in[5];
    const float* b1    = (const float*)d_in[6];
    const float* W2    = (const float*)d_in[7];
    const float* attl2 = (const float*)d_in[8];
    const float* attr2 = (const float*)d_in[9];
    const float* b2    = (const float*)d_in[10];

    const int* src = eidx;
    const int* dst = eidx + EE;

    // workspace layout
    __half* xlin1h = (__half*)d_ws;                            // N*64 f16
    __half* acc1h  = xlin1h + (size_t)NN * D1;                 // N*64 f16 residual
    __half* hh     = acc1h + (size_t)NN * D1;                  // N*64 f16 h
    unsigned short* hsum = (unsigned short*)(hh + (size_t)NN * D1);  // N*64 bf16
    float* al1   = (float*)(hsum + (size_t)NN * D1);           // N*4
    float* ar1   = al1 + (size_t)NN * HEADS;                   // N*4
    float* al2   = ar1 + (size_t)NN * HEADS;                   // N
    float* ar2   = al2 + NN;                                   // N
    float* vl    = ar2 + NN;                                   // 64
    float* vr    = vl + D1;                                    // 64
    unsigned short* Wtb  = (unsigned short*)(vr + D1);         // 144*128 bf16
    unsigned short* W2tb = Wtb + W1COLS * 128;                 // 64*64 bf16
    int* counts        = (int*)(W2tb + 64 * 64);               // N
    int* row_ptr       = counts + NN;                          // N
    int* bucket_cursor = row_ptr + NN;                         // 512
    int* sorted_src    = bucket_cursor + 512;                  // NB*BCAP = 2001920
    unsigned* binned = (unsigned*)d_out;    // NB*BCAP u32 = 8 MB; dead after binB

    float* out = (float*)d_out;

    // ---- prep + CSR build (binA fused with node1) ----
    prep_kernel<<<3, 512, 0, stream>>>(bucket_cursor, W1, resW1, W2,
                                       attl1, attr1, attl2, attr2,
                                       Wtb, W2tb, vl, vr);
    fusedA_kernel<<<BINA_BLOCKS + NODE_BLOCKS, 256, 0, stream>>>(
        src, dst, bucket_cursor, binned,
        x, Wtb, b1, xlin1h, acc1h, al1, ar1);
    binB_kernel<<<NB, 256, 0, stream>>>(binned, bucket_cursor,
                                        row_ptr, counts, sorted_src);

    // ---- layer 1 aggregation (+ residual + ELU + layer-2 dots) ----
    agg1_kernel<<<AGG_BLOCKS, 256, 0, stream>>>(sorted_src, row_ptr, counts,
                                                al1, ar1, xlin1h, acc1h, hh,
                                                vl, vr, al2, ar2);

    // ---- layer 2: aggregate h, then single GEMM ----
    agg2_kernel<<<AGG_BLOCKS, 256, 0, stream>>>(sorted_src, row_ptr, counts,
                                                al2, ar2, hh, hsum);
    node3_kernel<<<NODE_BLOCKS, 256, 0, stream>>>(hsum, W2tb, b2, out);
}